// Round 10
// baseline (724.170 us; speedup 1.0000x reference)
//
#include <hip/hip_runtime.h>
#include <math.h>

#define BB 16
#define NN 2000
#define CH 128
#define KNN 8
#define JCH 8
#define JSZ 250  // NN / JCH

// ---------------------------------------------------------------------------
// helpers
// ---------------------------------------------------------------------------
__device__ inline float wred(float v) {
    for (int off = 32; off > 0; off >>= 1) v += __shfl_down(v, off, 64);
    return v;
}

// conv1: c1[b,o,n] = sum_c w1a[o,c]*data[b,n,c] + b1a[o]
__global__ void k_conv1(const float* __restrict__ data, const float* __restrict__ w1a,
                        const float* __restrict__ b1a, float* __restrict__ c1) {
    int i = blockIdx.x * 256 + threadIdx.x;  // (b*128+o)*N+n
    if (i >= BB * CH * NN) return;
    int n = i % NN;
    int rest = i / NN;
    int o = rest & 127;
    int b = rest >> 7;
    const float4 d4 = *(const float4*)(data + (b * NN + n) * 4);
    const float4 w4 = *(const float4*)(w1a + o * 4);
    float acc = b1a[o];
    acc += w4.x * d4.x;
    acc += w4.y * d4.y;
    acc += w4.z * d4.z;
    acc += w4.w * d4.w;
    c1[i] = acc;
}

// per-channel bn stats over (b,n): 128 blocks
__global__ void k_chanstats(const float* __restrict__ src, float* __restrict__ chAB) {
    int o = blockIdx.x;
    int tid = threadIdx.x;
    float s = 0.f, ss = 0.f;
    for (int b = 0; b < BB; ++b) {
        const float* p = src + (b * CH + o) * NN;
        for (int n = tid; n < NN; n += 256) { float v = p[n]; s += v; ss += v * v; }
    }
    s = wred(s); ss = wred(ss);
    __shared__ float sh[8];
    int wid = tid >> 6, lane = tid & 63;
    if (lane == 0) { sh[wid] = s; sh[4 + wid] = ss; }
    __syncthreads();
    if (tid == 0) {
        float S0 = sh[0] + sh[1] + sh[2] + sh[3];
        float SS = sh[4] + sh[5] + sh[6] + sh[7];
        float m = S0 / (float)(BB * NN);
        float var = SS / (float)(BB * NN) - m * m;
        float a = rsqrtf(var + 1e-5f);
        chAB[o] = a;
        chAB[CH + o] = -m * a;
    }
}

// ---------------------------------------------------------------------------
// generic 128x128 GEMM over columns (b,n), with input transform.
// FMA accumulation order IDENTICAL to the r3 baseline — do not reorder.
// r17 version (verified passing at 719us in r19) — REVERTED here after the
// r20/r21 128x128-tile rewrite SIGABRT'd twice with no auditable OOB
// (config surface varied between the two attempts; both crashed -> the
// design itself faults; do NOT retry without disassembly access).
// ---------------------------------------------------------------------------
__global__ __launch_bounds__(256) void k_gemm(const float* __restrict__ X, const float* __restrict__ W,
                                              const float* __restrict__ bias, float* __restrict__ Y,
                                              const float* __restrict__ ab, int mode) {
    int ot = blockIdx.x, by = blockIdx.y;
    int b = by >> 5, nt = by & 31;
    int n0 = nt * 64, o0 = ot * 64;
    int tid = threadIdx.x;
    int tx = tid & 15, ty = tid >> 4;
    __shared__ __align__(16) float Xs[32][64];
    __shared__ __align__(16) float Ws[32][68];
    float acc[4][4] = {};
    for (int jc = 0; jc < 4; ++jc) {
        // X staging: 2048 floats = 512 quads; thread -> 2 quads
#pragma unroll
        for (int q = 0; q < 2; ++q) {
            int e4 = q * 256 + tid;          // 0..511
            int jj = e4 >> 4, nn4 = e4 & 15; // jj 0..31, nn4 0..15
            int j = jc * 32 + jj;
            int n = n0 + nn4 * 4;
            float4 v = make_float4(0.f, 0.f, 0.f, 0.f);
            if (n < NN) {  // quad all-in (n<=1996 => n+3<=1999) or all-out
                v = *(const float4*)&X[(b * CH + j) * NN + n];
                if (mode == 1) {
                    float a_ = ab[j], o_ = ab[CH + j];
                    v.x = fmaxf(a_ * v.x + o_, 0.f);
                    v.y = fmaxf(a_ * v.y + o_, 0.f);
                    v.z = fmaxf(a_ * v.z + o_, 0.f);
                    v.w = fmaxf(a_ * v.w + o_, 0.f);
                } else if (mode == 2) {
                    int bc = b * CH + j;
                    float a_ = ab[bc * 2], o_ = ab[bc * 2 + 1];
                    v.x = fmaxf(a_ * v.x + o_, 0.f);
                    v.y = fmaxf(a_ * v.y + o_, 0.f);
                    v.z = fmaxf(a_ * v.z + o_, 0.f);
                    v.w = fmaxf(a_ * v.w + o_, 0.f);
                }
            }
            *(float4*)&Xs[jj][nn4 * 4] = v;
        }
        // W staging: 2048 floats = 512 quads (contiguous in jj); transpose into Ws
#pragma unroll
        for (int q = 0; q < 2; ++q) {
            int e4 = q * 256 + tid;           // 0..511
            int oo = e4 >> 3, jj4 = e4 & 7;   // oo 0..63, jj4 0..7
            float4 wv4 = *(const float4*)&W[(o0 + oo) * CH + jc * 32 + jj4 * 4];
            Ws[jj4 * 4 + 0][oo] = wv4.x;
            Ws[jj4 * 4 + 1][oo] = wv4.y;
            Ws[jj4 * 4 + 2][oo] = wv4.z;
            Ws[jj4 * 4 + 3][oo] = wv4.w;
        }
        __syncthreads();
        for (int jj = 0; jj < 32; ++jj) {
            float4 wv = *(const float4*)&Ws[jj][ty * 4];
            float4 xv = *(const float4*)&Xs[jj][tx * 4];
            float wva[4] = {wv.x, wv.y, wv.z, wv.w};
            float xva[4] = {xv.x, xv.y, xv.z, xv.w};
#pragma unroll
            for (int a = 0; a < 4; ++a)
#pragma unroll
                for (int bq = 0; bq < 4; ++bq) acc[a][bq] += wva[a] * xva[bq];
        }
        __syncthreads();
    }
    for (int a = 0; a < 4; ++a) {
        int o = o0 + ty * 4 + a;
        float bi = bias[o];
        for (int q = 0; q < 4; ++q) {
            int n = n0 + tx * 4 + q;
            if (n < NN) Y[(b * CH + o) * NN + n] = acc[a][q] + bi;
        }
    }
}

// ---------------------------------------------------------------------------
// stage 1 tail: channel-norm, S, D, f5
// ---------------------------------------------------------------------------
__global__ void k_invn(const float* __restrict__ h2, float* __restrict__ invn) {
    int b = blockIdx.x >> 3, chunk = blockIdx.x & 7;
    int n = chunk * 256 + threadIdx.x;
    if (n >= NN) return;
    float acc = 0.f;
    for (int c = 0; c < CH; ++c) { float v = h2[(b * CH + c) * NN + n]; acc += v * v; }
    invn[b * NN + n] = 1.f / (sqrtf(acc) + 1e-5f);
}

__global__ void k_S(const float* __restrict__ h2, const float* __restrict__ invn, float* __restrict__ Sv) {
    int row = blockIdx.x;  // b*128+c
    int b = row >> 7;
    const float* p = h2 + row * NN;
    const float* iv = invn + b * NN;
    float s = 0.f;
    for (int n = threadIdx.x; n < NN; n += 256) s += p[n] * iv[n];
    s = wred(s);
    __shared__ float sh[4];
    int wid = threadIdx.x >> 6, lane = threadIdx.x & 63;
    if (lane == 0) sh[wid] = s;
    __syncthreads();
    if (threadIdx.x == 0) Sv[row] = sh[0] + sh[1] + sh[2] + sh[3];
}

__global__ void k_Df(const float* __restrict__ h2, const float* __restrict__ invn,
                     const float* __restrict__ Sv, const float* __restrict__ data,
                     float* __restrict__ outD, float* __restrict__ f5) {
    int b = blockIdx.x >> 3, chunk = blockIdx.x & 7;
    int n = chunk * 256 + threadIdx.x;
    if (n >= NN) return;
    float acc = 0.f;
    for (int c = 0; c < CH; ++c) acc += h2[(b * CH + c) * NN + n] * Sv[b * CH + c];
    float Ar = acc * invn[b * NN + n];
    float Dv = (Ar - 1.0f) / (float)NN;
    outD[b * NN + n] = Dv;
    const float4 d4 = *(const float4*)(data + (b * NN + n) * 4);
    f5[(b * 5 + 0) * NN + n] = d4.x;
    f5[(b * 5 + 1) * NN + n] = d4.y;
    f5[(b * 5 + 2) * NN + n] = d4.z;
    f5[(b * 5 + 3) * NN + n] = d4.w;
    f5[(b * 5 + 4) * NN + n] = fmaxf(tanhf(Dv), 0.f);
}

// ---------------------------------------------------------------------------
// kNN stage A (r16): branchless selection on separate (f32 d, i32 j) with
// single-native-compare CAS: 1 v_cmp_lt_f32 (vcc) + 4 v_cndmask, zero SALU.
// Tie-break-free strict < is selection-identical: no exact f32 ties among
// real candidates; self = +inf; pad sentinels never reach top-8.
// ---------------------------------------------------------------------------
__device__ __forceinline__ void cas_fj(float& da, int& ja, float& db, int& jb) {
    bool sw = db < da;
    float d0 = sw ? db : da;
    float d1 = sw ? da : db;
    int j0 = sw ? jb : ja;
    int j1 = sw ? ja : jb;
    da = d0; db = d1; ja = j0; jb = j1;
}

__global__ __launch_bounds__(256, 4) void k_knn_part(const float* __restrict__ f5,
                                                     float* __restrict__ pd, int* __restrict__ pj) {
    __shared__ float4 fs4[256];
    __shared__ float fs1[256];
    int jc = blockIdx.x, ic = blockIdx.y, b = blockIdx.z;
    int j0 = jc * JSZ;
    int tid = threadIdx.x;
    const float* fb = f5 + b * 5 * NN;
    if (tid < JSZ) {
        float4 v;
        v.x = fb[0 * NN + j0 + tid];
        v.y = fb[1 * NN + j0 + tid];
        v.z = fb[2 * NN + j0 + tid];
        v.w = fb[3 * NN + j0 + tid];
        fs4[tid] = v;
        fs1[tid] = fb[4 * NN + j0 + tid];
    } else {
        fs4[tid] = make_float4(1e18f, 1e18f, 1e18f, 1e18f);
        fs1[tid] = 1e18f;
    }
    __syncthreads();
    int i = ic * 256 + tid;
    if (i >= NN) return;
    float fi0 = fb[i], fi1 = fb[NN + i], fi2 = fb[2 * NN + i], fi3 = fb[3 * NN + i], fi4 = fb[4 * NN + i];
    const float DINF = __int_as_float(0x7f800000);
    float bd[8]; int bj[8];
#pragma unroll
    for (int q = 0; q < 8; ++q) { bd[q] = 1e30f; bj[q] = 0x7fffffff; }
    for (int g = 0; g < 256; g += 8) {
        float gd[8]; int gj[8];
#pragma unroll
        for (int k = 0; k < 8; ++k) {
            float4 fj = fs4[g + k];
            float f4 = fs1[g + k];
            float a0 = fi0 - fj.x, a1 = fi1 - fj.y, a2 = fi2 - fj.z, a3 = fi3 - fj.w, a4 = fi4 - f4;
            float dd = a0 * a0 + a1 * a1 + a2 * a2 + a3 * a3 + a4 * a4;
            int jj = j0 + g + k;
            gd[k] = (jj == i) ? DINF : dd;
            gj[k] = jj;
        }
        // Batcher odd-even mergesort for 8 (19 comparators), ascending
        cas_fj(gd[0], gj[0], gd[1], gj[1]); cas_fj(gd[2], gj[2], gd[3], gj[3]);
        cas_fj(gd[4], gj[4], gd[5], gj[5]); cas_fj(gd[6], gj[6], gd[7], gj[7]);
        cas_fj(gd[0], gj[0], gd[2], gj[2]); cas_fj(gd[1], gj[1], gd[3], gj[3]);
        cas_fj(gd[4], gj[4], gd[6], gj[6]); cas_fj(gd[5], gj[5], gd[7], gj[7]);
        cas_fj(gd[1], gj[1], gd[2], gj[2]); cas_fj(gd[5], gj[5], gd[6], gj[6]);
        cas_fj(gd[0], gj[0], gd[4], gj[4]); cas_fj(gd[1], gj[1], gd[5], gj[5]);
        cas_fj(gd[2], gj[2], gd[6], gj[6]); cas_fj(gd[3], gj[3], gd[7], gj[7]);
        cas_fj(gd[2], gj[2], gd[4], gj[4]); cas_fj(gd[3], gj[3], gd[5], gj[5]);
        cas_fj(gd[1], gj[1], gd[2], gj[2]); cas_fj(gd[3], gj[3], gd[4], gj[4]);
        cas_fj(gd[5], gj[5], gd[6], gj[6]);
        // lowest-8 of (bd asc ++ gd desc): elementwise min IN PLACE -> bitonic
#pragma unroll
        for (int q = 0; q < 8; ++q) {
            float yd = gd[7 - q]; int yj = gj[7 - q];
            bool kp = bd[q] < yd;
            bd[q] = kp ? bd[q] : yd;
            bj[q] = kp ? bj[q] : yj;
        }
        // bitonic cleanup of the 8-length bitonic sequence (12 CAS), in place
        cas_fj(bd[0], bj[0], bd[4], bj[4]); cas_fj(bd[1], bj[1], bd[5], bj[5]);
        cas_fj(bd[2], bj[2], bd[6], bj[6]); cas_fj(bd[3], bj[3], bd[7], bj[7]);
        cas_fj(bd[0], bj[0], bd[2], bj[2]); cas_fj(bd[1], bj[1], bd[3], bj[3]);
        cas_fj(bd[4], bj[4], bd[6], bj[6]); cas_fj(bd[5], bj[5], bd[7], bj[7]);
        cas_fj(bd[0], bj[0], bd[1], bj[1]); cas_fj(bd[2], bj[2], bd[3], bj[3]);
        cas_fj(bd[4], bj[4], bd[5], bj[5]); cas_fj(bd[6], bj[6], bd[7], bj[7]);
    }
    long base = ((long)(b * NN + i) * JCH + jc) * 8;
#pragma unroll
    for (int q = 0; q < 8; ++q) { pd[base + q] = bd[q]; pj[base + q] = bj[q]; }
}

// kNN stage B: 8-way merge of sorted partial lists (separate kernel — r12's
// fusion with gstats spilled registers and regressed; reverted).
__global__ __launch_bounds__(256) void k_knn_merge(const float* __restrict__ pd, const int* __restrict__ pj,
                                                   int* __restrict__ idxb) {
    int s = blockIdx.x * 256 + threadIdx.x;  // b*NN + i
    if (s >= BB * NN) return;
    const float* dl = pd + (long)s * JCH * 8;
    const int* jl = pj + (long)s * JCH * 8;
    int ptr[JCH];
#pragma unroll
    for (int c = 0; c < JCH; ++c) ptr[c] = 0;
    for (int q = 0; q < 8; ++q) {
        float best = 1e38f; int bestj = 0x7fffffff; int bc = 0;
#pragma unroll
        for (int c = 0; c < JCH; ++c) {
            if (ptr[c] < 8) {
                float d = dl[c * 8 + ptr[c]];
                int j = jl[c * 8 + ptr[c]];
                if (d < best || (d == best && j < bestj)) { best = d; bestj = j; bc = c; }
            }
        }
        idxb[s * 8 + q] = bestj;
        ++ptr[bc];
    }
}

// ---------------------------------------------------------------------------
// graph-feature statistics: 10 means + 55 second moments (f64 accumulators)
// ---------------------------------------------------------------------------
__global__ __launch_bounds__(128) void k_gstats(const float* __restrict__ f5, const int* __restrict__ idxb,
                                                double* __restrict__ gacc) {
    int s = blockIdx.x * 128 + threadIdx.x;
    float acc[65];
#pragma unroll
    for (int q = 0; q < 65; ++q) acc[q] = 0.f;
    if (s < BB * NN) {
        int b = s / NN, n = s - b * NN;
        float fo[5];
#pragma unroll
        for (int c = 0; c < 5; ++c) fo[c] = f5[(b * 5 + c) * NN + n];
        float sd[5] = {0, 0, 0, 0, 0};
        float sdd[15];
#pragma unroll
        for (int q = 0; q < 15; ++q) sdd[q] = 0.f;
        for (int k = 0; k < 8; ++k) {
            int j = idxb[s * 8 + k];
            float df[5];
#pragma unroll
            for (int c = 0; c < 5; ++c) df[c] = fo[c] - f5[(b * 5 + c) * NN + j];
#pragma unroll
            for (int c = 0; c < 5; ++c) sd[c] += df[c];
            int t = 0;
#pragma unroll
            for (int c = 0; c < 5; ++c)
#pragma unroll
                for (int d2 = c; d2 < 5; ++d2) { sdd[t] += df[c] * df[d2]; ++t; }
        }
#pragma unroll
        for (int c = 0; c < 5; ++c) { acc[c] = 8.f * fo[c]; acc[5 + c] = sd[c]; }
        int t = 10, sc = 0;
        for (int p = 0; p < 10; ++p)
            for (int q = p; q < 10; ++q) {
                float v;
                if (q < 5) v = 8.f * fo[p] * fo[q];
                else if (p < 5) v = fo[p] * sd[q - 5];
                else { v = sdd[sc]; ++sc; }
                acc[t++] = v;
            }
    }
#pragma unroll 1
    for (int q = 0; q < 65; ++q) {
        float v = acc[q];
        for (int off = 32; off > 0; off >>= 1) v += __shfl_down(v, off, 64);
        acc[q] = v;
    }
    __shared__ float sh[2][65];
    int lane = threadIdx.x & 63, wid = threadIdx.x >> 6;
    if (lane == 0) {
        for (int q = 0; q < 65; ++q) sh[wid][q] = acc[q];
    }
    __syncthreads();
    if (threadIdx.x < 65) {
        float tot = sh[0][threadIdx.x] + sh[1][threadIdx.x];
        atomicAdd(&gacc[threadIdx.x], (double)tot);
    }
}

__global__ void k_gfinal(const double* __restrict__ gacc, const float* __restrict__ w2,
                         const float* __restrict__ b2, float* __restrict__ g2ab) {
    int o = threadIdx.x;
    if (o >= 128) return;
    double inv = 1.0 / (double)(BB * NN * 8);
    double Wr[10];
    for (int c = 0; c < 10; ++c) Wr[c] = (double)w2[o * 10 + c];
    double gm[10];
    for (int c = 0; c < 10; ++c) gm[c] = gacc[c] * inv;
    double b0 = (double)b2[o];
    double mean = b0;
    for (int c = 0; c < 10; ++c) mean += Wr[c] * gm[c];
    double e2 = b0 * b0 + 2.0 * b0 * (mean - b0);
    int t = 10;
    for (int p = 0; p < 10; ++p)
        for (int q = p; q < 10; ++q) {
            double G = gacc[t] * inv; ++t;
            double contrib = Wr[p] * Wr[q] * G;
            e2 += (p == q) ? contrib : 2.0 * contrib;
        }
    double var = e2 - mean * mean;
    double a = 1.0 / sqrt(var + 1e-5);
    g2ab[o] = (float)a;
    g2ab[128 + o] = (float)(-mean * a);
}

// graph conv + max over k + bn + relu (bn commutes with max since scale>0)
__global__ __launch_bounds__(256) void k_graphconv(const float* __restrict__ f5, const int* __restrict__ idxb,
                                                   const float* __restrict__ w2, const float* __restrict__ b2,
                                                   const float* __restrict__ g2ab, float* __restrict__ x0) {
    __shared__ float ws[1280], bs[128];
    __shared__ float fo_s[16][5], fnb_s[16][8][5];
    __shared__ int idxs[16][8];
    int b = blockIdx.x / 125, tile = blockIdx.x % 125;
    int nbase = tile * 16;
    int tid = threadIdx.x;
    for (int e = tid; e < 1280; e += 256) ws[e] = w2[e];
    if (tid < 128) bs[tid] = b2[tid];
    if (tid < 128) { int nn = tid >> 3, k = tid & 7; idxs[nn][k] = idxb[(b * NN + nbase + nn) * 8 + k]; }
    if (tid >= 128 && tid < 208) { int e = tid - 128; int nn = e / 5, c = e % 5; fo_s[nn][c] = f5[(b * 5 + c) * NN + nbase + nn]; }
    __syncthreads();
    for (int e = tid; e < 640; e += 256) {
        int nn = e / 40, r = e % 40, k = r / 5, c = r % 5;
        fnb_s[nn][k][c] = f5[(b * 5 + c) * NN + idxs[nn][k]];
    }
    __syncthreads();
    int nn = tid & 15, og = tid >> 4;
    float fo[5];
#pragma unroll
    for (int c = 0; c < 5; ++c) fo[c] = fo_s[nn][c];
    for (int oo = 0; oo < 8; ++oo) {
        int o = og * 8 + oo;
        float base = bs[o];
        float wn[5];
#pragma unroll
        for (int c = 0; c < 5; ++c) {
            float w1 = ws[o * 10 + c], w5 = ws[o * 10 + 5 + c];
            base += (w1 + w5) * fo[c];
            wn[c] = w5;
        }
        float mx = -1e30f;
        for (int k = 0; k < 8; ++k) {
            float v = base;
#pragma unroll
            for (int c = 0; c < 5; ++c) v -= wn[c] * fnb_s[nn][k][c];
            mx = fmaxf(mx, v);
        }
        float y = fmaxf(g2ab[o] * mx + g2ab[128 + o], 0.f);
        x0[(b * CH + o) * NN + nbase + nn] = y;
    }
}

// ---------------------------------------------------------------------------
// res-block support — r11 structure (r12's last-block finalize added a
// serial latency tail at each dispatch end and regressed; reverted).
// ---------------------------------------------------------------------------
__global__ void k_rowstats(const float* __restrict__ src, float* __restrict__ stats) {
    int row = blockIdx.x;  // b*128+c
    const float* p = src + row * NN;
    float s = 0.f, ss = 0.f;
    for (int n = threadIdx.x; n < NN; n += 256) { float v = p[n]; s += v; ss += v * v; }
    s = wred(s); ss = wred(ss);
    __shared__ float sh[8];
    int wid = threadIdx.x >> 6, lane = threadIdx.x & 63;
    if (lane == 0) { sh[wid] = s; sh[4 + wid] = ss; }
    __syncthreads();
    if (threadIdx.x == 0) {
        float S0 = sh[0] + sh[1] + sh[2] + sh[3];
        float SS = sh[4] + sh[5] + sh[6] + sh[7];
        float m = S0 / (float)NN;
        float var = SS / (float)NN - m * m;
        stats[row * 2] = m;
        stats[row * 2 + 1] = var;
    }
}

__global__ void k_finalize(const float* __restrict__ stats, float* __restrict__ ab) {
    int c = threadIdx.x;
    if (c >= 128) return;
    float acc = 0.f;
    for (int b = 0; b < BB; ++b) { float var = stats[(b * CH + c) * 2 + 1]; acc += var / (var + 1e-5f); }
    float vc = acc / (float)BB;
    float sc = rsqrtf(vc + 1e-5f);
    for (int b = 0; b < BB; ++b) {
        float m = stats[(b * CH + c) * 2];
        float var = stats[(b * CH + c) * 2 + 1];
        float a = rsqrtf(var + 1e-5f) * sc;
        ab[(b * CH + c) * 2] = a;
        ab[(b * CH + c) * 2 + 1] = -m * a;
    }
}

// r22: float4 vectorized (4 | NN so a quad never crosses a row boundary ->
// bc uniform per quad; per-element expression unchanged -> bit-identical).
__global__ void k_resadd(const float* __restrict__ Bm, const float* __restrict__ ab,
                         const float* __restrict__ x, float* __restrict__ y) {
    int i4 = blockIdx.x * 256 + threadIdx.x;  // quad index
    if (i4 >= BB * CH * NN / 4) return;
    int base = i4 * 4;
    int bc = base / NN;
    float a_ = ab[bc * 2], o_ = ab[bc * 2 + 1];
    const float4 Bv = *(const float4*)(Bm + base);
    const float4 xv = *(const float4*)(x + base);
    float4 yv;
    yv.x = fmaxf(a_ * Bv.x + o_ + xv.x, 0.f);
    yv.y = fmaxf(a_ * Bv.y + o_ + xv.y, 0.f);
    yv.z = fmaxf(a_ * Bv.z + o_ + xv.z, 0.f);
    yv.w = fmaxf(a_ * Bv.w + o_ + xv.w, 0.f);
    *(float4*)(y + base) = yv;
}

// ---------------------------------------------------------------------------
// logit (separate — r10 lesson: never move work into a smaller grid)
// ---------------------------------------------------------------------------
__global__ void k_logit(const float* __restrict__ x4, const float* __restrict__ wl,
                        const float* __restrict__ bl, float* __restrict__ outLogit) {
    int b = blockIdx.x >> 3, chunk = blockIdx.x & 7;
    int n = chunk * 256 + threadIdx.x;
    if (n >= NN) return;
    float acc = 0.f;
    for (int c = 0; c < CH; ++c) acc += wl[c] * x4[(b * CH + c) * NN + n];
    outLogit[b * NN + n] = acc + bl[0];
}

__global__ __launch_bounds__(256) void k_xwx(const float* __restrict__ logit, const float* __restrict__ x_in,
                                             float* __restrict__ XwX) {
    int b = blockIdx.x;
    int tid = threadIdx.x;
    float a[45];
#pragma unroll
    for (int q = 0; q < 45; ++q) a[q] = 0.f;
    for (int n = tid; n < NN; n += 256) {
        float lg = logit[b * NN + n];
        float w = fmaxf(tanhf(lg), 0.f);
        const float* xp = x_in + (b * NN + n) * 4;
        float px = xp[0], py = xp[1], z = xp[2], wq = xp[3];
        float X9[9] = {z * px, z * py, z, wq * px, wq * py, wq, px, py, 1.f};
        int t = 0;
#pragma unroll
        for (int p = 0; p < 9; ++p) {
            float wp = w * X9[p];
#pragma unroll
            for (int q = p; q < 9; ++q) { a[t] += wp * X9[q]; ++t; }
        }
    }
#pragma unroll 1
    for (int q = 0; q < 45; ++q) {
        float v = a[q];
        for (int off = 32; off > 0; off >>= 1) v += __shfl_down(v, off, 64);
        a[q] = v;
    }
    __shared__ float sh[4][45];
    int lane = tid & 63, wid = tid >> 6;
    if (lane == 0) {
        for (int q = 0; q < 45; ++q) sh[wid][q] = a[q];
    }
    __syncthreads();
    if (tid < 45) XwX[b * 45 + tid] = sh[0][tid] + sh[1][tid] + sh[2][tid] + sh[3][tid];
}

// ---------------------------------------------------------------------------
// 9x9 symmetric eigensolver — faithful LAPACK ssyevd (f32) emulation:
// ssytd2 (lower) + ssteqr + sormtr, f32 LAPACK constants, 3.10+ slartg.
// ARITHMETIC verified passing r10/r11 — unchanged.
// r19 (verified passing): full unroll -> p/w/updv in registers, no scratch;
// batched LDS reads; lane-0 publishes guarded by __syncthreads() pairs.
// ---------------------------------------------------------------------------
__device__ __forceinline__ float lgetf(float reg, int i) {
    return __int_as_float(__builtin_amdgcn_readlane(__float_as_int(reg), i));
}
__device__ __forceinline__ float wsum64(float v) {
    for (int off = 32; off > 0; off >>= 1) v += __shfl_xor(v, off, 64);
    return v;
}

__device__ inline float slapy2_f(float x, float y) {
    float xa = fabsf(x), ya = fabsf(y);
    float w = fmaxf(xa, ya), z = fminf(xa, ya);
    if (z == 0.f) return w;
    float q = z / w;
    return w * sqrtf(1.f + q * q);
}

__device__ inline void slartg_f(float f, float g, float& c, float& s, float& r) {
    if (g == 0.f) { c = 1.f; s = 0.f; r = f; }
    else if (f == 0.f) { c = 0.f; s = (g > 0.f ? 1.f : -1.f); r = fabsf(g); }
    else {
        float d = sqrtf(f * f + g * g);
        c = fabsf(f) / d;
        r = (f >= 0.f) ? d : -d;
        s = g / r;
    }
}

__device__ void slaev2_f(float a, float b, float c, float& rt1, float& rt2, float& cs1, float& sn1) {
    float sm = a + c, df = a - c;
    float adf = fabsf(df), tb = b + b, ab = fabsf(tb);
    float acmx, acmn;
    if (fabsf(a) > fabsf(c)) { acmx = a; acmn = c; } else { acmx = c; acmn = a; }
    float rt;
    if (adf > ab) { float q = ab / adf; rt = adf * sqrtf(1.f + q * q); }
    else if (adf < ab) { float q = adf / ab; rt = ab * sqrtf(1.f + q * q); }
    else rt = ab * sqrtf(2.f);
    int sgn1;
    if (sm < 0.f) { rt1 = 0.5f * (sm - rt); sgn1 = -1; rt2 = (acmx / rt1) * acmn - (b / rt1) * b; }
    else if (sm > 0.f) { rt1 = 0.5f * (sm + rt); sgn1 = 1; rt2 = (acmx / rt1) * acmn - (b / rt1) * b; }
    else { rt1 = 0.5f * rt; rt2 = -0.5f * rt; sgn1 = 1; }
    float cs; int sgn2;
    if (df >= 0.f) { cs = df + rt; sgn2 = 1; } else { cs = df - rt; sgn2 = -1; }
    float acs = fabsf(cs);
    if (acs > ab) {
        float ct = -tb / cs;
        sn1 = 1.f / sqrtf(1.f + ct * ct);
        cs1 = ct * sn1;
    } else {
        if (ab == 0.f) { cs1 = 1.f; sn1 = 0.f; }
        else { float tn = -cs / tb; cs1 = 1.f / sqrtf(1.f + tn * tn); sn1 = tn * cs1; }
    }
    if (sgn1 == sgn2) { float tn = cs1; cs1 = -sn1; sn1 = tn; }
}

#define ROTLOG_MAX 2560

__global__ __launch_bounds__(64) void k_eigh(const float* __restrict__ XwX, float* __restrict__ out_e) {
    __shared__ float Am[81];
    __shared__ float rcl[ROTLOG_MAX], rsl[ROTLOG_MAX];
    __shared__ int rjl[ROTLOG_MAX];
    int bb = blockIdx.x;
    int lane = threadIdx.x;
#define AA(i, j) Am[(i) * 9 + (j)]
#define DGET(i) lgetf(dreg, (i))
#define DSET(i, v) do { float _v = (v); dreg = (lane == (i)) ? _v : dreg; } while (0)
#define EGET(i) lgetf(ereg, (i))
#define ESET(i, v) do { float _v = (v); ereg = (lane == (i)) ? _v : ereg; } while (0)
    {
        const float* src = XwX + bb * 45;
        for (int e2 = lane; e2 < 81; e2 += 64) {
            int r0 = e2 / 9, c0 = e2 % 9;
            int a0 = r0 < c0 ? r0 : c0, b0 = r0 < c0 ? c0 : r0;
            int t = a0 * 9 - (a0 * (a0 - 1)) / 2 + (b0 - a0);
            Am[e2] = src[t];
        }
    }
    __syncthreads();
    float dreg = 0.f, ereg = 0.f, treg = 0.f;
    int cnt = 0;
#pragma unroll
    for (int i = 0; i < 8; ++i) {
        float alpha = AA(i + 1, i);
        float xn2 = 0.f;
#pragma unroll
        for (int j = i + 2; j < 9; ++j) xn2 += AA(j, i) * AA(j, i);
        float taui;
        if (xn2 == 0.f) { taui = 0.f; ESET(i, alpha); }
        else {
            float xnorm = sqrtf(xn2);
            float beta = slapy2_f(alpha, xnorm);
            beta = (alpha >= 0.f) ? -beta : beta;
            taui = (beta - alpha) / beta;
            float scl = 1.f / (alpha - beta);
            float colv[9];
#pragma unroll
            for (int j = i + 2; j < 9; ++j) colv[j] = AA(j, i) * scl;
            __syncthreads();
            if (lane == 0) {
#pragma unroll
                for (int j = i + 2; j < 9; ++j) AA(j, i) = colv[j];
            }
            __syncthreads();
            ESET(i, beta);
            float p[9], w[9];
#pragma unroll
            for (int j = i + 1; j < 9; ++j) {
                float acc = AA(j, i + 1);
#pragma unroll
                for (int k2 = i + 2; k2 < 9; ++k2) acc += AA(j, k2) * AA(k2, i);
                p[j] = taui * acc;
            }
            float dot = p[i + 1];
#pragma unroll
            for (int j = i + 2; j < 9; ++j) dot += p[j] * AA(j, i);
            float alpha2 = -0.5f * taui * dot;
            w[i + 1] = p[i + 1] + alpha2;
#pragma unroll
            for (int j = i + 2; j < 9; ++j) w[j] = p[j] + alpha2 * AA(j, i);
            float updv[9][9];
#pragma unroll
            for (int j = i + 1; j < 9; ++j) {
                float vj = (j == i + 1) ? 1.f : AA(j, i);
#pragma unroll
                for (int k2 = i + 1; k2 < 9; ++k2) {
                    float vk = (k2 == i + 1) ? 1.f : AA(k2, i);
                    updv[j][k2] = AA(j, k2) - (vj * w[k2] + w[j] * vk);
                }
            }
            __syncthreads();
            if (lane == 0) {
#pragma unroll
                for (int j = i + 1; j < 9; ++j)
#pragma unroll
                    for (int k2 = i + 1; k2 < 9; ++k2)
                        AA(j, k2) = updv[j][k2];
            }
            __syncthreads();
        }
        treg = (lane == i) ? taui : treg;
    }
    __syncthreads();
    dreg = (lane < 9) ? Am[lane * 10] : 0.f;
    const float eps = 5.9604645e-08f;
    const float eps2 = 3.5527137e-15f;
    const float safmin = 1.17549435e-38f;
    const int n = 9;
    int nmaxit = n * 30, jtot = 0;
    int l1 = 0;
    while (l1 <= n - 1) {
        if (l1 > 0) ESET(l1 - 1, 0.f);
        int m = n - 1;
        for (int mm = l1; mm <= n - 2; ++mm) {
            float tst = fabsf(EGET(mm));
            if (tst == 0.f) { m = mm; break; }
            if (tst <= (sqrtf(fabsf(DGET(mm))) * sqrtf(fabsf(DGET(mm + 1)))) * eps) { ESET(mm, 0.f); m = mm; break; }
        }
        int l = l1, lsv = l, lend = m, lendsv = lend;
        l1 = m + 1;
        if (lend == l) continue;
        if (fabsf(DGET(lend)) < fabsf(DGET(l))) { lend = lsv; l = lendsv; }
        if (lend > l) {
            for (;;) {
                int m2 = lend;
                if (l != lend) {
                    for (int mm = l; mm <= lend - 1; ++mm) {
                        float em = EGET(mm);
                        float tst = em * em;
                        if (tst <= (eps2 * fabsf(DGET(mm))) * fabsf(DGET(mm + 1)) + safmin) { m2 = mm; break; }
                    }
                }
                if (m2 < lend) ESET(m2, 0.f);
                float p = DGET(l);
                if (m2 == l) { DSET(l, p); ++l; if (l <= lend) continue; else break; }
                if (m2 == l + 1) {
                    float rt1, rt2, c, s;
                    slaev2_f(DGET(l), EGET(l), DGET(l + 1), rt1, rt2, c, s);
                    if (lane == 0) { rcl[cnt] = c; rsl[cnt] = s; rjl[cnt] = l; }
                    ++cnt;
                    DSET(l, rt1); DSET(l + 1, rt2); ESET(l, 0.f); l += 2;
                    if (l <= lend) continue; else break;
                }
                if (jtot == nmaxit) break;
                ++jtot;
                float g = (DGET(l + 1) - p) / (2.f * EGET(l));
                float r = slapy2_f(g, 1.f);
                g = DGET(m2) - p + EGET(l) / (g + (g >= 0.f ? fabsf(r) : -fabsf(r)));
                float s = 1.f, c = 1.f;
                p = 0.f;
                for (int i = m2 - 1; i >= l; --i) {
                    float ei = EGET(i);
                    float f = s * ei, bq = c * ei;
                    slartg_f(g, f, c, s, r);
                    if (i != m2 - 1) ESET(i + 1, r);
                    g = DGET(i + 1) - p;
                    r = (DGET(i) - g) * s + 2.f * c * bq;
                    p = s * r;
                    DSET(i + 1, g + p);
                    g = c * r - bq;
                    if (lane == 0) { rcl[cnt] = c; rsl[cnt] = -s; rjl[cnt] = i; }
                    ++cnt;
                }
                DSET(l, DGET(l) - p);
                ESET(l, g);
            }
        } else {
            for (;;) {
                int m2 = lend;
                if (l != lend) {
                    for (int mm = l; mm >= lend + 1; --mm) {
                        float em = EGET(mm - 1);
                        float tst = em * em;
                        if (tst <= (eps2 * fabsf(DGET(mm))) * fabsf(DGET(mm - 1)) + safmin) { m2 = mm; break; }
                    }
                }
                if (m2 > lend) ESET(m2 - 1, 0.f);
                float p = DGET(l);
                if (m2 == l) { DSET(l, p); --l; if (l >= lend) continue; else break; }
                if (m2 == l - 1) {
                    float rt1, rt2, c, s;
                    slaev2_f(DGET(l - 1), EGET(l - 1), DGET(l), rt1, rt2, c, s);
                    if (lane == 0) { rcl[cnt] = c; rsl[cnt] = s; rjl[cnt] = l - 1; }
                    ++cnt;
                    DSET(l - 1, rt1); DSET(l, rt2); ESET(l - 1, 0.f); l -= 2;
                    if (l >= lend) continue; else break;
                }
                if (jtot == nmaxit) break;
                ++jtot;
                float g = (DGET(l - 1) - p) / (2.f * EGET(l - 1));
                float r = slapy2_f(g, 1.f);
                g = DGET(m2) - p + EGET(l - 1) / (g + (g >= 0.f ? fabsf(r) : -fabsf(r)));
                float s = 1.f, c = 1.f;
                p = 0.f;
                for (int i = m2; i <= l - 1; ++i) {
                    float ei = EGET(i);
                    float f = s * ei, bq = c * ei;
                    slartg_f(g, f, c, s, r);
                    if (i != m2) ESET(i - 1, r);
                    g = DGET(i) - p;
                    r = (DGET(i + 1) - g) * s + 2.f * c * bq;
                    p = s * r;
                    DSET(i, g + p);
                    g = c * r - bq;
                    if (lane == 0) { rcl[cnt] = c; rsl[cnt] = s; rjl[cnt] = i; }
                    ++cnt;
                }
                DSET(l, DGET(l) - p);
                ESET(l - 1, g);
            }
        }
    }
    __syncthreads();
    int permreg = lane;
    for (int ii = 1; ii < 9; ++ii) {
        int i = ii - 1, kk = i;
        float p = DGET(i);
        for (int j = ii; j < 9; ++j) {
            float dj = DGET(j);
            if (dj < p) { kk = j; p = dj; }
        }
        if (kk != i) {
            float di = DGET(i);
            DSET(kk, di);
            DSET(i, p);
            int pi = __builtin_amdgcn_readlane(permreg, i);
            int pk = __builtin_amdgcn_readlane(permreg, kk);
            permreg = (lane == i) ? pk : permreg;
            permreg = (lane == kk) ? pi : permreg;
        }
    }
    int kcol = __builtin_amdgcn_readlane(permreg, 0);
    float v0reg = (lane == kcol) ? 1.f : 0.f;
    for (int t = cnt - 1; t >= 0; --t) {
        float c = rcl[t], s = rsl[t];
        int j = rjl[t];
        float a = lgetf(v0reg, j);
        float b2 = lgetf(v0reg, j + 1);
        float nj = c * a - s * b2;
        float nj1 = s * a + c * b2;
        v0reg = (lane == j) ? nj : v0reg;
        v0reg = (lane == j + 1) ? nj1 : v0reg;
    }
    for (int i = 7; i >= 0; --i) {
        float ti = lgetf(treg, i);
        if (ti == 0.f) continue;
        float avi = (lane >= i + 2 && lane <= 8) ? Am[lane * 9 + i] : 0.f;
        float contrib = 0.f;
        if (lane == i + 1) contrib = v0reg;
        else if (lane >= i + 2 && lane <= 8) contrib = avi * v0reg;
        float dot = wsum64(contrib) * ti;
        if (lane == i + 1) v0reg -= dot;
        else if (lane >= i + 2 && lane <= 8) v0reg -= avi * dot;
    }
    float sq = (lane < 9) ? v0reg * v0reg : 0.f;
    float nrm = sqrtf(wsum64(sq));
    if (lane < 9) out_e[bb * 9 + lane] = v0reg / nrm;
#undef AA
#undef DGET
#undef DSET
#undef EGET
#undef ESET
}

// ---------------------------------------------------------------------------
// launch
// ---------------------------------------------------------------------------
extern "C" void kernel_launch(void* const* d_in, const int* in_sizes, int n_in,
                              void* d_out, int out_size, void* d_ws, size_t ws_size,
                              hipStream_t stream) {
    const float* data = (const float*)d_in[0];
    const float* x_in = (const float*)d_in[1];
    const float* w1a = (const float*)d_in[2];
    const float* b1a = (const float*)d_in[3];
    const float* w1b = (const float*)d_in[4];
    const float* b1b = (const float*)d_in[5];
    const float* w2 = (const float*)d_in[6];
    const float* b2 = (const float*)d_in[7];
    const float* res_wa = (const float*)d_in[8];
    const float* res_ba = (const float*)d_in[9];
    const float* res_wb = (const float*)d_in[10];
    const float* res_bb = (const float*)d_in[11];
    const float* wl = (const float*)d_in[12];
    const float* bl = (const float*)d_in[13];
    float* out = (float*)d_out;

    // workspace layout
    double* gacc = (double*)d_ws;                       // 65 doubles (zeroed)
    float* xwx = (float*)((char*)d_ws + 1024);          // 16*45 floats
    float* fbase = (float*)((char*)d_ws + 16384);
    float* big0 = fbase;
    float* big1 = big0 + BB * CH * NN;
    float* big2 = big1 + BB * CH * NN;
    float* tbuf = big2 + BB * CH * NN;  // unused
    float* f5 = tbuf + BB * 4 * NN;
    float* invn = f5 + BB * 5 * NN;
    float* Sv = invn + BB * NN;
    int* idxb = (int*)(Sv + BB * CH);
    float* chAB = (float*)(idxb + BB * NN * 8);
    float* stA = chAB + 256;
    float* abA = stA + BB * CH * 2;
    float* stB = abA + BB * CH * 2;
    float* abB = stB + BB * CH * 2;
    float* g2ab = abB + BB * CH * 2;
    // kNN partials live in big2 (free until the res-blocks)
    float* knn_pd = big2;
    int* knn_pj = (int*)(big2 + BB * NN * JCH * 8);

    hipMemsetAsync(d_ws, 0, 1024, stream);

    k_conv1<<<16000, 256, 0, stream>>>(data, w1a, b1a, big0);
    k_chanstats<<<128, 256, 0, stream>>>(big0, chAB);
    k_gemm<<<dim3(2, 512), 256, 0, stream>>>(big0, w1b, b1b, big1, chAB, 1);  // h2 in big1
    k_invn<<<128, 256, 0, stream>>>(big1, invn);
    k_S<<<2048, 256, 0, stream>>>(big1, invn, Sv);
    k_Df<<<128, 256, 0, stream>>>(big1, invn, Sv, data, out, f5);
    k_knn_part<<<dim3(JCH, 8, BB), 256, 0, stream>>>(f5, knn_pd, knn_pj);
    k_knn_merge<<<125, 256, 0, stream>>>(knn_pd, knn_pj, idxb);
    k_gstats<<<250, 128, 0, stream>>>(f5, idxb, gacc);
    k_gfinal<<<1, 128, 0, stream>>>(gacc, w2, b2, g2ab);
    k_graphconv<<<2000, 256, 0, stream>>>(f5, idxb, w2, b2, g2ab, big0);  // x0 in big0

    float* xb = big0;
    float* hb = big1;
    for (int i = 0; i < 4; ++i) {
        k_gemm<<<dim3(2, 512), 256, 0, stream>>>(xb, res_wa + i * CH * CH, res_ba + i * CH, hb, nullptr, 0);
        k_rowstats<<<2048, 256, 0, stream>>>(hb, stA);
        k_finalize<<<1, 128, 0, stream>>>(stA, abA);
        k_gemm<<<dim3(2, 512), 256, 0, stream>>>(hb, res_wb + i * CH * CH, res_bb + i * CH, big2, abA, 2);
        k_rowstats<<<2048, 256, 0, stream>>>(big2, stB);
        k_finalize<<<1, 128, 0, stream>>>(stB, abB);
        k_resadd<<<4000, 256, 0, stream>>>(big2, abB, xb, hb);
        float* tmp = xb; xb = hb; hb = tmp;
    }

    k_logit<<<128, 256, 0, stream>>>(xb, wl, bl, out + BB * NN);
    k_xwx<<<16, 256, 0, stream>>>(out + BB * NN, x_in, xwx);
    k_eigh<<<16, 64, 0, stream>>>(xwx, out + 2 * BB * NN);
}

// Round 11
// 708.929 us; speedup vs baseline: 1.0215x; 1.0215x over previous
//
#include <hip/hip_runtime.h>
#include <math.h>

#define BB 16
#define NN 2000
#define CH 128
#define KNN 8
#define JCH 8
#define JSZ 250  // NN / JCH

// ---------------------------------------------------------------------------
// helpers
// ---------------------------------------------------------------------------
__device__ inline float wred(float v) {
    for (int off = 32; off > 0; off >>= 1) v += __shfl_down(v, off, 64);
    return v;
}

// conv1: c1[b,o,n] = sum_c w1a[o,c]*data[b,n,c] + b1a[o]
__global__ void k_conv1(const float* __restrict__ data, const float* __restrict__ w1a,
                        const float* __restrict__ b1a, float* __restrict__ c1) {
    int i = blockIdx.x * 256 + threadIdx.x;  // (b*128+o)*N+n
    if (i >= BB * CH * NN) return;
    int n = i % NN;
    int rest = i / NN;
    int o = rest & 127;
    int b = rest >> 7;
    const float4 d4 = *(const float4*)(data + (b * NN + n) * 4);
    const float4 w4 = *(const float4*)(w1a + o * 4);
    float acc = b1a[o];
    acc += w4.x * d4.x;
    acc += w4.y * d4.y;
    acc += w4.z * d4.z;
    acc += w4.w * d4.w;
    c1[i] = acc;
}

// per-channel bn stats over (b,n): 128 blocks
__global__ void k_chanstats(const float* __restrict__ src, float* __restrict__ chAB) {
    int o = blockIdx.x;
    int tid = threadIdx.x;
    float s = 0.f, ss = 0.f;
    for (int b = 0; b < BB; ++b) {
        const float* p = src + (b * CH + o) * NN;
        for (int n = tid; n < NN; n += 256) { float v = p[n]; s += v; ss += v * v; }
    }
    s = wred(s); ss = wred(ss);
    __shared__ float sh[8];
    int wid = tid >> 6, lane = tid & 63;
    if (lane == 0) { sh[wid] = s; sh[4 + wid] = ss; }
    __syncthreads();
    if (tid == 0) {
        float S0 = sh[0] + sh[1] + sh[2] + sh[3];
        float SS = sh[4] + sh[5] + sh[6] + sh[7];
        float m = S0 / (float)(BB * NN);
        float var = SS / (float)(BB * NN) - m * m;
        float a = rsqrtf(var + 1e-5f);
        chAB[o] = a;
        chAB[CH + o] = -m * a;
    }
}

// ---------------------------------------------------------------------------
// generic 128x128 GEMM over columns (b,n), with input transform.
// FMA accumulation order IDENTICAL to the r3 baseline — do not reorder.
// r17 version (verified passing) — the r20/r21 128x128-tile rewrite
// SIGABRT'd twice with no auditable OOB; do NOT retry without disassembly.
// ---------------------------------------------------------------------------
__global__ __launch_bounds__(256) void k_gemm(const float* __restrict__ X, const float* __restrict__ W,
                                              const float* __restrict__ bias, float* __restrict__ Y,
                                              const float* __restrict__ ab, int mode) {
    int ot = blockIdx.x, by = blockIdx.y;
    int b = by >> 5, nt = by & 31;
    int n0 = nt * 64, o0 = ot * 64;
    int tid = threadIdx.x;
    int tx = tid & 15, ty = tid >> 4;
    __shared__ __align__(16) float Xs[32][64];
    __shared__ __align__(16) float Ws[32][68];
    float acc[4][4] = {};
    for (int jc = 0; jc < 4; ++jc) {
        // X staging: 2048 floats = 512 quads; thread -> 2 quads
#pragma unroll
        for (int q = 0; q < 2; ++q) {
            int e4 = q * 256 + tid;          // 0..511
            int jj = e4 >> 4, nn4 = e4 & 15; // jj 0..31, nn4 0..15
            int j = jc * 32 + jj;
            int n = n0 + nn4 * 4;
            float4 v = make_float4(0.f, 0.f, 0.f, 0.f);
            if (n < NN) {  // quad all-in (n<=1996 => n+3<=1999) or all-out
                v = *(const float4*)&X[(b * CH + j) * NN + n];
                if (mode == 1) {
                    float a_ = ab[j], o_ = ab[CH + j];
                    v.x = fmaxf(a_ * v.x + o_, 0.f);
                    v.y = fmaxf(a_ * v.y + o_, 0.f);
                    v.z = fmaxf(a_ * v.z + o_, 0.f);
                    v.w = fmaxf(a_ * v.w + o_, 0.f);
                } else if (mode == 2) {
                    int bc = b * CH + j;
                    float a_ = ab[bc * 2], o_ = ab[bc * 2 + 1];
                    v.x = fmaxf(a_ * v.x + o_, 0.f);
                    v.y = fmaxf(a_ * v.y + o_, 0.f);
                    v.z = fmaxf(a_ * v.z + o_, 0.f);
                    v.w = fmaxf(a_ * v.w + o_, 0.f);
                }
            }
            *(float4*)&Xs[jj][nn4 * 4] = v;
        }
        // W staging: 2048 floats = 512 quads (contiguous in jj); transpose into Ws
#pragma unroll
        for (int q = 0; q < 2; ++q) {
            int e4 = q * 256 + tid;           // 0..511
            int oo = e4 >> 3, jj4 = e4 & 7;   // oo 0..63, jj4 0..7
            float4 wv4 = *(const float4*)&W[(o0 + oo) * CH + jc * 32 + jj4 * 4];
            Ws[jj4 * 4 + 0][oo] = wv4.x;
            Ws[jj4 * 4 + 1][oo] = wv4.y;
            Ws[jj4 * 4 + 2][oo] = wv4.z;
            Ws[jj4 * 4 + 3][oo] = wv4.w;
        }
        __syncthreads();
        for (int jj = 0; jj < 32; ++jj) {
            float4 wv = *(const float4*)&Ws[jj][ty * 4];
            float4 xv = *(const float4*)&Xs[jj][tx * 4];
            float wva[4] = {wv.x, wv.y, wv.z, wv.w};
            float xva[4] = {xv.x, xv.y, xv.z, xv.w};
#pragma unroll
            for (int a = 0; a < 4; ++a)
#pragma unroll
                for (int bq = 0; bq < 4; ++bq) acc[a][bq] += wva[a] * xva[bq];
        }
        __syncthreads();
    }
    for (int a = 0; a < 4; ++a) {
        int o = o0 + ty * 4 + a;
        float bi = bias[o];
        for (int q = 0; q < 4; ++q) {
            int n = n0 + tx * 4 + q;
            if (n < NN) Y[(b * CH + o) * NN + n] = acc[a][q] + bi;
        }
    }
}

// ---------------------------------------------------------------------------
// stage 1 tail: channel-norm, S, D, f5
// ---------------------------------------------------------------------------
__global__ void k_invn(const float* __restrict__ h2, float* __restrict__ invn) {
    int b = blockIdx.x >> 3, chunk = blockIdx.x & 7;
    int n = chunk * 256 + threadIdx.x;
    if (n >= NN) return;
    float acc = 0.f;
    for (int c = 0; c < CH; ++c) { float v = h2[(b * CH + c) * NN + n]; acc += v * v; }
    invn[b * NN + n] = 1.f / (sqrtf(acc) + 1e-5f);
}

__global__ void k_S(const float* __restrict__ h2, const float* __restrict__ invn, float* __restrict__ Sv) {
    int row = blockIdx.x;  // b*128+c
    int b = row >> 7;
    const float* p = h2 + row * NN;
    const float* iv = invn + b * NN;
    float s = 0.f;
    for (int n = threadIdx.x; n < NN; n += 256) s += p[n] * iv[n];
    s = wred(s);
    __shared__ float sh[4];
    int wid = threadIdx.x >> 6, lane = threadIdx.x & 63;
    if (lane == 0) sh[wid] = s;
    __syncthreads();
    if (threadIdx.x == 0) Sv[row] = sh[0] + sh[1] + sh[2] + sh[3];
}

__global__ void k_Df(const float* __restrict__ h2, const float* __restrict__ invn,
                     const float* __restrict__ Sv, const float* __restrict__ data,
                     float* __restrict__ outD, float* __restrict__ f5) {
    int b = blockIdx.x >> 3, chunk = blockIdx.x & 7;
    int n = chunk * 256 + threadIdx.x;
    if (n >= NN) return;
    float acc = 0.f;
    for (int c = 0; c < CH; ++c) acc += h2[(b * CH + c) * NN + n] * Sv[b * CH + c];
    float Ar = acc * invn[b * NN + n];
    float Dv = (Ar - 1.0f) / (float)NN;
    outD[b * NN + n] = Dv;
    const float4 d4 = *(const float4*)(data + (b * NN + n) * 4);
    f5[(b * 5 + 0) * NN + n] = d4.x;
    f5[(b * 5 + 1) * NN + n] = d4.y;
    f5[(b * 5 + 2) * NN + n] = d4.z;
    f5[(b * 5 + 3) * NN + n] = d4.w;
    f5[(b * 5 + 4) * NN + n] = fmaxf(tanhf(Dv), 0.f);
}

// ---------------------------------------------------------------------------
// kNN stage A (r16): branchless selection on separate (f32 d, i32 j) with
// single-native-compare CAS: 1 v_cmp_lt_f32 (vcc) + 4 v_cndmask, zero SALU.
// Tie-break-free strict < is selection-identical: no exact f32 ties among
// real candidates; self = +inf; pad sentinels never reach top-8.
// ---------------------------------------------------------------------------
__device__ __forceinline__ void cas_fj(float& da, int& ja, float& db, int& jb) {
    bool sw = db < da;
    float d0 = sw ? db : da;
    float d1 = sw ? da : db;
    int j0 = sw ? jb : ja;
    int j1 = sw ? ja : jb;
    da = d0; db = d1; ja = j0; jb = j1;
}

__global__ __launch_bounds__(256, 4) void k_knn_part(const float* __restrict__ f5,
                                                     float* __restrict__ pd, int* __restrict__ pj) {
    __shared__ float4 fs4[256];
    __shared__ float fs1[256];
    int jc = blockIdx.x, ic = blockIdx.y, b = blockIdx.z;
    int j0 = jc * JSZ;
    int tid = threadIdx.x;
    const float* fb = f5 + b * 5 * NN;
    if (tid < JSZ) {
        float4 v;
        v.x = fb[0 * NN + j0 + tid];
        v.y = fb[1 * NN + j0 + tid];
        v.z = fb[2 * NN + j0 + tid];
        v.w = fb[3 * NN + j0 + tid];
        fs4[tid] = v;
        fs1[tid] = fb[4 * NN + j0 + tid];
    } else {
        fs4[tid] = make_float4(1e18f, 1e18f, 1e18f, 1e18f);
        fs1[tid] = 1e18f;
    }
    __syncthreads();
    int i = ic * 256 + tid;
    if (i >= NN) return;
    float fi0 = fb[i], fi1 = fb[NN + i], fi2 = fb[2 * NN + i], fi3 = fb[3 * NN + i], fi4 = fb[4 * NN + i];
    const float DINF = __int_as_float(0x7f800000);
    float bd[8]; int bj[8];
#pragma unroll
    for (int q = 0; q < 8; ++q) { bd[q] = 1e30f; bj[q] = 0x7fffffff; }
    for (int g = 0; g < 256; g += 8) {
        float gd[8]; int gj[8];
#pragma unroll
        for (int k = 0; k < 8; ++k) {
            float4 fj = fs4[g + k];
            float f4 = fs1[g + k];
            float a0 = fi0 - fj.x, a1 = fi1 - fj.y, a2 = fi2 - fj.z, a3 = fi3 - fj.w, a4 = fi4 - f4;
            float dd = a0 * a0 + a1 * a1 + a2 * a2 + a3 * a3 + a4 * a4;
            int jj = j0 + g + k;
            gd[k] = (jj == i) ? DINF : dd;
            gj[k] = jj;
        }
        // Batcher odd-even mergesort for 8 (19 comparators), ascending
        cas_fj(gd[0], gj[0], gd[1], gj[1]); cas_fj(gd[2], gj[2], gd[3], gj[3]);
        cas_fj(gd[4], gj[4], gd[5], gj[5]); cas_fj(gd[6], gj[6], gd[7], gj[7]);
        cas_fj(gd[0], gj[0], gd[2], gj[2]); cas_fj(gd[1], gj[1], gd[3], gj[3]);
        cas_fj(gd[4], gj[4], gd[6], gj[6]); cas_fj(gd[5], gj[5], gd[7], gj[7]);
        cas_fj(gd[1], gj[1], gd[2], gj[2]); cas_fj(gd[5], gj[5], gd[6], gj[6]);
        cas_fj(gd[0], gj[0], gd[4], gj[4]); cas_fj(gd[1], gj[1], gd[5], gj[5]);
        cas_fj(gd[2], gj[2], gd[6], gj[6]); cas_fj(gd[3], gj[3], gd[7], gj[7]);
        cas_fj(gd[2], gj[2], gd[4], gj[4]); cas_fj(gd[3], gj[3], gd[5], gj[5]);
        cas_fj(gd[1], gj[1], gd[2], gj[2]); cas_fj(gd[3], gj[3], gd[4], gj[4]);
        cas_fj(gd[5], gj[5], gd[6], gj[6]);
        // lowest-8 of (bd asc ++ gd desc): elementwise min IN PLACE -> bitonic
#pragma unroll
        for (int q = 0; q < 8; ++q) {
            float yd = gd[7 - q]; int yj = gj[7 - q];
            bool kp = bd[q] < yd;
            bd[q] = kp ? bd[q] : yd;
            bj[q] = kp ? bj[q] : yj;
        }
        // bitonic cleanup of the 8-length bitonic sequence (12 CAS), in place
        cas_fj(bd[0], bj[0], bd[4], bj[4]); cas_fj(bd[1], bj[1], bd[5], bj[5]);
        cas_fj(bd[2], bj[2], bd[6], bj[6]); cas_fj(bd[3], bj[3], bd[7], bj[7]);
        cas_fj(bd[0], bj[0], bd[2], bj[2]); cas_fj(bd[1], bj[1], bd[3], bj[3]);
        cas_fj(bd[4], bj[4], bd[6], bj[6]); cas_fj(bd[5], bj[5], bd[7], bj[7]);
        cas_fj(bd[0], bj[0], bd[1], bj[1]); cas_fj(bd[2], bj[2], bd[3], bj[3]);
        cas_fj(bd[4], bj[4], bd[5], bj[5]); cas_fj(bd[6], bj[6], bd[7], bj[7]);
    }
    long base = ((long)(b * NN + i) * JCH + jc) * 8;
#pragma unroll
    for (int q = 0; q < 8; ++q) { pd[base + q] = bd[q]; pj[base + q] = bj[q]; }
}

// kNN stage B: 8-way merge of sorted partial lists (separate kernel — r12's
// fusion with gstats spilled registers and regressed; reverted).
__global__ __launch_bounds__(256) void k_knn_merge(const float* __restrict__ pd, const int* __restrict__ pj,
                                                   int* __restrict__ idxb) {
    int s = blockIdx.x * 256 + threadIdx.x;  // b*NN + i
    if (s >= BB * NN) return;
    const float* dl = pd + (long)s * JCH * 8;
    const int* jl = pj + (long)s * JCH * 8;
    int ptr[JCH];
#pragma unroll
    for (int c = 0; c < JCH; ++c) ptr[c] = 0;
    for (int q = 0; q < 8; ++q) {
        float best = 1e38f; int bestj = 0x7fffffff; int bc = 0;
#pragma unroll
        for (int c = 0; c < JCH; ++c) {
            if (ptr[c] < 8) {
                float d = dl[c * 8 + ptr[c]];
                int j = jl[c * 8 + ptr[c]];
                if (d < best || (d == best && j < bestj)) { best = d; bestj = j; bc = c; }
            }
        }
        idxb[s * 8 + q] = bestj;
        ++ptr[bc];
    }
}

// ---------------------------------------------------------------------------
// graph-feature statistics: 10 means + 55 second moments (f64 accumulators)
// ---------------------------------------------------------------------------
__global__ __launch_bounds__(128) void k_gstats(const float* __restrict__ f5, const int* __restrict__ idxb,
                                                double* __restrict__ gacc) {
    int s = blockIdx.x * 128 + threadIdx.x;
    float acc[65];
#pragma unroll
    for (int q = 0; q < 65; ++q) acc[q] = 0.f;
    if (s < BB * NN) {
        int b = s / NN, n = s - b * NN;
        float fo[5];
#pragma unroll
        for (int c = 0; c < 5; ++c) fo[c] = f5[(b * 5 + c) * NN + n];
        float sd[5] = {0, 0, 0, 0, 0};
        float sdd[15];
#pragma unroll
        for (int q = 0; q < 15; ++q) sdd[q] = 0.f;
        for (int k = 0; k < 8; ++k) {
            int j = idxb[s * 8 + k];
            float df[5];
#pragma unroll
            for (int c = 0; c < 5; ++c) df[c] = fo[c] - f5[(b * 5 + c) * NN + j];
#pragma unroll
            for (int c = 0; c < 5; ++c) sd[c] += df[c];
            int t = 0;
#pragma unroll
            for (int c = 0; c < 5; ++c)
#pragma unroll
                for (int d2 = c; d2 < 5; ++d2) { sdd[t] += df[c] * df[d2]; ++t; }
        }
#pragma unroll
        for (int c = 0; c < 5; ++c) { acc[c] = 8.f * fo[c]; acc[5 + c] = sd[c]; }
        int t = 10, sc = 0;
        for (int p = 0; p < 10; ++p)
            for (int q = p; q < 10; ++q) {
                float v;
                if (q < 5) v = 8.f * fo[p] * fo[q];
                else if (p < 5) v = fo[p] * sd[q - 5];
                else { v = sdd[sc]; ++sc; }
                acc[t++] = v;
            }
    }
#pragma unroll 1
    for (int q = 0; q < 65; ++q) {
        float v = acc[q];
        for (int off = 32; off > 0; off >>= 1) v += __shfl_down(v, off, 64);
        acc[q] = v;
    }
    __shared__ float sh[2][65];
    int lane = threadIdx.x & 63, wid = threadIdx.x >> 6;
    if (lane == 0) {
        for (int q = 0; q < 65; ++q) sh[wid][q] = acc[q];
    }
    __syncthreads();
    if (threadIdx.x < 65) {
        float tot = sh[0][threadIdx.x] + sh[1][threadIdx.x];
        atomicAdd(&gacc[threadIdx.x], (double)tot);
    }
}

__global__ void k_gfinal(const double* __restrict__ gacc, const float* __restrict__ w2,
                         const float* __restrict__ b2, float* __restrict__ g2ab) {
    int o = threadIdx.x;
    if (o >= 128) return;
    double inv = 1.0 / (double)(BB * NN * 8);
    double Wr[10];
    for (int c = 0; c < 10; ++c) Wr[c] = (double)w2[o * 10 + c];
    double gm[10];
    for (int c = 0; c < 10; ++c) gm[c] = gacc[c] * inv;
    double b0 = (double)b2[o];
    double mean = b0;
    for (int c = 0; c < 10; ++c) mean += Wr[c] * gm[c];
    double e2 = b0 * b0 + 2.0 * b0 * (mean - b0);
    int t = 10;
    for (int p = 0; p < 10; ++p)
        for (int q = p; q < 10; ++q) {
            double G = gacc[t] * inv; ++t;
            double contrib = Wr[p] * Wr[q] * G;
            e2 += (p == q) ? contrib : 2.0 * contrib;
        }
    double var = e2 - mean * mean;
    double a = 1.0 / sqrt(var + 1e-5);
    g2ab[o] = (float)a;
    g2ab[128 + o] = (float)(-mean * a);
}

// graph conv + max over k + bn + relu (bn commutes with max since scale>0)
__global__ __launch_bounds__(256) void k_graphconv(const float* __restrict__ f5, const int* __restrict__ idxb,
                                                   const float* __restrict__ w2, const float* __restrict__ b2,
                                                   const float* __restrict__ g2ab, float* __restrict__ x0) {
    __shared__ float ws[1280], bs[128];
    __shared__ float fo_s[16][5], fnb_s[16][8][5];
    __shared__ int idxs[16][8];
    int b = blockIdx.x / 125, tile = blockIdx.x % 125;
    int nbase = tile * 16;
    int tid = threadIdx.x;
    for (int e = tid; e < 1280; e += 256) ws[e] = w2[e];
    if (tid < 128) bs[tid] = b2[tid];
    if (tid < 128) { int nn = tid >> 3, k = tid & 7; idxs[nn][k] = idxb[(b * NN + nbase + nn) * 8 + k]; }
    if (tid >= 128 && tid < 208) { int e = tid - 128; int nn = e / 5, c = e % 5; fo_s[nn][c] = f5[(b * 5 + c) * NN + nbase + nn]; }
    __syncthreads();
    for (int e = tid; e < 640; e += 256) {
        int nn = e / 40, r = e % 40, k = r / 5, c = r % 5;
        fnb_s[nn][k][c] = f5[(b * 5 + c) * NN + idxs[nn][k]];
    }
    __syncthreads();
    int nn = tid & 15, og = tid >> 4;
    float fo[5];
#pragma unroll
    for (int c = 0; c < 5; ++c) fo[c] = fo_s[nn][c];
    for (int oo = 0; oo < 8; ++oo) {
        int o = og * 8 + oo;
        float base = bs[o];
        float wn[5];
#pragma unroll
        for (int c = 0; c < 5; ++c) {
            float w1 = ws[o * 10 + c], w5 = ws[o * 10 + 5 + c];
            base += (w1 + w5) * fo[c];
            wn[c] = w5;
        }
        float mx = -1e30f;
        for (int k = 0; k < 8; ++k) {
            float v = base;
#pragma unroll
            for (int c = 0; c < 5; ++c) v -= wn[c] * fnb_s[nn][k][c];
            mx = fmaxf(mx, v);
        }
        float y = fmaxf(g2ab[o] * mx + g2ab[128 + o], 0.f);
        x0[(b * CH + o) * NN + nbase + nn] = y;
    }
}

// ---------------------------------------------------------------------------
// res-block support — r11 structure.
// ---------------------------------------------------------------------------
__global__ void k_rowstats(const float* __restrict__ src, float* __restrict__ stats) {
    int row = blockIdx.x;  // b*128+c
    const float* p = src + row * NN;
    float s = 0.f, ss = 0.f;
    for (int n = threadIdx.x; n < NN; n += 256) { float v = p[n]; s += v; ss += v * v; }
    s = wred(s); ss = wred(ss);
    __shared__ float sh[8];
    int wid = threadIdx.x >> 6, lane = threadIdx.x & 63;
    if (lane == 0) { sh[wid] = s; sh[4 + wid] = ss; }
    __syncthreads();
    if (threadIdx.x == 0) {
        float S0 = sh[0] + sh[1] + sh[2] + sh[3];
        float SS = sh[4] + sh[5] + sh[6] + sh[7];
        float m = S0 / (float)NN;
        float var = SS / (float)NN - m * m;
        stats[row * 2] = m;
        stats[row * 2 + 1] = var;
    }
}

__global__ void k_finalize(const float* __restrict__ stats, float* __restrict__ ab) {
    int c = threadIdx.x;
    if (c >= 128) return;
    float acc = 0.f;
    for (int b = 0; b < BB; ++b) { float var = stats[(b * CH + c) * 2 + 1]; acc += var / (var + 1e-5f); }
    float vc = acc / (float)BB;
    float sc = rsqrtf(vc + 1e-5f);
    for (int b = 0; b < BB; ++b) {
        float m = stats[(b * CH + c) * 2];
        float var = stats[(b * CH + c) * 2 + 1];
        float a = rsqrtf(var + 1e-5f) * sc;
        ab[(b * CH + c) * 2] = a;
        ab[(b * CH + c) * 2 + 1] = -m * a;
    }
}

// r22: float4 vectorized (4 | NN so a quad never crosses a row boundary ->
// bc uniform per quad; per-element expression unchanged -> bit-identical).
__global__ void k_resadd(const float* __restrict__ Bm, const float* __restrict__ ab,
                         const float* __restrict__ x, float* __restrict__ y) {
    int i4 = blockIdx.x * 256 + threadIdx.x;  // quad index
    if (i4 >= BB * CH * NN / 4) return;
    int base = i4 * 4;
    int bc = base / NN;
    float a_ = ab[bc * 2], o_ = ab[bc * 2 + 1];
    const float4 Bv = *(const float4*)(Bm + base);
    const float4 xv = *(const float4*)(x + base);
    float4 yv;
    yv.x = fmaxf(a_ * Bv.x + o_ + xv.x, 0.f);
    yv.y = fmaxf(a_ * Bv.y + o_ + xv.y, 0.f);
    yv.z = fmaxf(a_ * Bv.z + o_ + xv.z, 0.f);
    yv.w = fmaxf(a_ * Bv.w + o_ + xv.w, 0.f);
    *(float4*)(y + base) = yv;
}

// ---------------------------------------------------------------------------
// logit (separate — r10 lesson: never move work into a smaller grid)
// ---------------------------------------------------------------------------
__global__ void k_logit(const float* __restrict__ x4, const float* __restrict__ wl,
                        const float* __restrict__ bl, float* __restrict__ outLogit) {
    int b = blockIdx.x >> 3, chunk = blockIdx.x & 7;
    int n = chunk * 256 + threadIdx.x;
    if (n >= NN) return;
    float acc = 0.f;
    for (int c = 0; c < CH; ++c) acc += wl[c] * x4[(b * CH + c) * NN + n];
    outLogit[b * NN + n] = acc + bl[0];
}

__global__ __launch_bounds__(256) void k_xwx(const float* __restrict__ logit, const float* __restrict__ x_in,
                                             float* __restrict__ XwX) {
    int b = blockIdx.x;
    int tid = threadIdx.x;
    float a[45];
#pragma unroll
    for (int q = 0; q < 45; ++q) a[q] = 0.f;
    for (int n = tid; n < NN; n += 256) {
        float lg = logit[b * NN + n];
        float w = fmaxf(tanhf(lg), 0.f);
        const float* xp = x_in + (b * NN + n) * 4;
        float px = xp[0], py = xp[1], z = xp[2], wq = xp[3];
        float X9[9] = {z * px, z * py, z, wq * px, wq * py, wq, px, py, 1.f};
        int t = 0;
#pragma unroll
        for (int p = 0; p < 9; ++p) {
            float wp = w * X9[p];
#pragma unroll
            for (int q = p; q < 9; ++q) { a[t] += wp * X9[q]; ++t; }
        }
    }
#pragma unroll 1
    for (int q = 0; q < 45; ++q) {
        float v = a[q];
        for (int off = 32; off > 0; off >>= 1) v += __shfl_down(v, off, 64);
        a[q] = v;
    }
    __shared__ float sh[4][45];
    int lane = tid & 63, wid = tid >> 6;
    if (lane == 0) {
        for (int q = 0; q < 45; ++q) sh[wid][q] = a[q];
    }
    __syncthreads();
    if (tid < 45) XwX[b * 45 + tid] = sh[0][tid] + sh[1][tid] + sh[2][tid] + sh[3][tid];
}

// ---------------------------------------------------------------------------
// 9x9 symmetric eigensolver — faithful LAPACK ssyevd (f32) emulation:
// ssytd2 (lower) + ssteqr + sormtr. ARITHMETIC verified — unchanged.
// r19 (verified passing): batched LDS reads; lane-0 publishes guarded by
// __syncthreads() pairs.
// r23: Householder outer i-loop DE-UNROLLED (runtime i). Rationale: FETCH
// grew 117->140->195KB with unrolling while input is 2.9KB — instruction
// fetch; a single serial wave streams straight-line code with no icache
// reuse and nothing to hide fetch latency. Inner loops stay unrolled 0..8
// with WAVE-UNIFORM guards (i uniform -> branches skip; executed ops
// identical in identical order -> bit-identical). p/w/updv keep compile-
// time indices (SROA -> registers, no scratch, rule #20). Runtime p[i+1]/
// w[i+1] accesses folded into j==i+1 assignment arms (assign, not add).
// Barriers preserved exactly as r19 (r18's barrier-free publish FAILED).
// ---------------------------------------------------------------------------
__device__ __forceinline__ float lgetf(float reg, int i) {
    return __int_as_float(__builtin_amdgcn_readlane(__float_as_int(reg), i));
}
__device__ __forceinline__ float wsum64(float v) {
    for (int off = 32; off > 0; off >>= 1) v += __shfl_xor(v, off, 64);
    return v;
}

__device__ inline float slapy2_f(float x, float y) {
    float xa = fabsf(x), ya = fabsf(y);
    float w = fmaxf(xa, ya), z = fminf(xa, ya);
    if (z == 0.f) return w;
    float q = z / w;
    return w * sqrtf(1.f + q * q);
}

__device__ inline void slartg_f(float f, float g, float& c, float& s, float& r) {
    if (g == 0.f) { c = 1.f; s = 0.f; r = f; }
    else if (f == 0.f) { c = 0.f; s = (g > 0.f ? 1.f : -1.f); r = fabsf(g); }
    else {
        float d = sqrtf(f * f + g * g);
        c = fabsf(f) / d;
        r = (f >= 0.f) ? d : -d;
        s = g / r;
    }
}

__device__ void slaev2_f(float a, float b, float c, float& rt1, float& rt2, float& cs1, float& sn1) {
    float sm = a + c, df = a - c;
    float adf = fabsf(df), tb = b + b, ab = fabsf(tb);
    float acmx, acmn;
    if (fabsf(a) > fabsf(c)) { acmx = a; acmn = c; } else { acmx = c; acmn = a; }
    float rt;
    if (adf > ab) { float q = ab / adf; rt = adf * sqrtf(1.f + q * q); }
    else if (adf < ab) { float q = adf / ab; rt = ab * sqrtf(1.f + q * q); }
    else rt = ab * sqrtf(2.f);
    int sgn1;
    if (sm < 0.f) { rt1 = 0.5f * (sm - rt); sgn1 = -1; rt2 = (acmx / rt1) * acmn - (b / rt1) * b; }
    else if (sm > 0.f) { rt1 = 0.5f * (sm + rt); sgn1 = 1; rt2 = (acmx / rt1) * acmn - (b / rt1) * b; }
    else { rt1 = 0.5f * rt; rt2 = -0.5f * rt; sgn1 = 1; }
    float cs; int sgn2;
    if (df >= 0.f) { cs = df + rt; sgn2 = 1; } else { cs = df - rt; sgn2 = -1; }
    float acs = fabsf(cs);
    if (acs > ab) {
        float ct = -tb / cs;
        sn1 = 1.f / sqrtf(1.f + ct * ct);
        cs1 = ct * sn1;
    } else {
        if (ab == 0.f) { cs1 = 1.f; sn1 = 0.f; }
        else { float tn = -cs / tb; cs1 = 1.f / sqrtf(1.f + tn * tn); sn1 = tn * cs1; }
    }
    if (sgn1 == sgn2) { float tn = cs1; cs1 = -sn1; sn1 = tn; }
}

#define ROTLOG_MAX 2560

__global__ __launch_bounds__(64) void k_eigh(const float* __restrict__ XwX, float* __restrict__ out_e) {
    __shared__ float Am[81];
    __shared__ float rcl[ROTLOG_MAX], rsl[ROTLOG_MAX];
    __shared__ int rjl[ROTLOG_MAX];
    int bb = blockIdx.x;
    int lane = threadIdx.x;
#define AA(i, j) Am[(i) * 9 + (j)]
#define DGET(i) lgetf(dreg, (i))
#define DSET(i, v) do { float _v = (v); dreg = (lane == (i)) ? _v : dreg; } while (0)
#define EGET(i) lgetf(ereg, (i))
#define ESET(i, v) do { float _v = (v); ereg = (lane == (i)) ? _v : ereg; } while (0)
    {
        const float* src = XwX + bb * 45;
        for (int e2 = lane; e2 < 81; e2 += 64) {
            int r0 = e2 / 9, c0 = e2 % 9;
            int a0 = r0 < c0 ? r0 : c0, b0 = r0 < c0 ? c0 : r0;
            int t = a0 * 9 - (a0 * (a0 - 1)) / 2 + (b0 - a0);
            Am[e2] = src[t];
        }
    }
    __syncthreads();
    float dreg = 0.f, ereg = 0.f, treg = 0.f;
    int cnt = 0;
    // r23: runtime i, uniform-guarded unrolled inner loops (see header).
    for (int i = 0; i < 8; ++i) {
        float alpha = AA(i + 1, i);
        float xn2 = 0.f;
#pragma unroll
        for (int j = 0; j < 9; ++j)
            if (j >= i + 2) xn2 += AA(j, i) * AA(j, i);
        float taui;
        if (xn2 == 0.f) { taui = 0.f; ESET(i, alpha); }
        else {
            float xnorm = sqrtf(xn2);
            float beta = slapy2_f(alpha, xnorm);
            beta = (alpha >= 0.f) ? -beta : beta;
            taui = (beta - alpha) / beta;
            float scl = 1.f / (alpha - beta);
            float colv[9];
#pragma unroll
            for (int j = 0; j < 9; ++j)
                if (j >= i + 2) colv[j] = AA(j, i) * scl;
            __syncthreads();
            if (lane == 0) {
#pragma unroll
                for (int j = 0; j < 9; ++j)
                    if (j >= i + 2) AA(j, i) = colv[j];
            }
            __syncthreads();
            ESET(i, beta);
            float p[9], w[9];
#pragma unroll
            for (int j = 0; j < 9; ++j)
                if (j >= i + 1) {
                    float acc = AA(j, i + 1);
#pragma unroll
                    for (int k2 = 0; k2 < 9; ++k2)
                        if (k2 >= i + 2) acc += AA(j, k2) * AA(k2, i);
                    p[j] = taui * acc;
                }
            float dot = 0.f;
#pragma unroll
            for (int j = 0; j < 9; ++j) {
                if (j == i + 1) dot = p[j];                 // assign (order: first)
                else if (j >= i + 2) dot += p[j] * AA(j, i);
            }
            float alpha2 = -0.5f * taui * dot;
#pragma unroll
            for (int j = 0; j < 9; ++j) {
                if (j == i + 1) w[j] = p[j] + alpha2;
                else if (j >= i + 2) w[j] = p[j] + alpha2 * AA(j, i);
            }
            float updv[9][9];
#pragma unroll
            for (int j = 0; j < 9; ++j)
                if (j >= i + 1) {
                    float vj = (j == i + 1) ? 1.f : AA(j, i);
#pragma unroll
                    for (int k2 = 0; k2 < 9; ++k2)
                        if (k2 >= i + 1) {
                            float vk = (k2 == i + 1) ? 1.f : AA(k2, i);
                            updv[j][k2] = AA(j, k2) - (vj * w[k2] + w[j] * vk);
                        }
                }
            __syncthreads();
            if (lane == 0) {
#pragma unroll
                for (int j = 0; j < 9; ++j)
                    if (j >= i + 1) {
#pragma unroll
                        for (int k2 = 0; k2 < 9; ++k2)
                            if (k2 >= i + 1) AA(j, k2) = updv[j][k2];
                    }
            }
            __syncthreads();
        }
        treg = (lane == i) ? taui : treg;
    }
    __syncthreads();
    dreg = (lane < 9) ? Am[lane * 10] : 0.f;
    const float eps = 5.9604645e-08f;
    const float eps2 = 3.5527137e-15f;
    const float safmin = 1.17549435e-38f;
    const int n = 9;
    int nmaxit = n * 30, jtot = 0;
    int l1 = 0;
    while (l1 <= n - 1) {
        if (l1 > 0) ESET(l1 - 1, 0.f);
        int m = n - 1;
        for (int mm = l1; mm <= n - 2; ++mm) {
            float tst = fabsf(EGET(mm));
            if (tst == 0.f) { m = mm; break; }
            if (tst <= (sqrtf(fabsf(DGET(mm))) * sqrtf(fabsf(DGET(mm + 1)))) * eps) { ESET(mm, 0.f); m = mm; break; }
        }
        int l = l1, lsv = l, lend = m, lendsv = lend;
        l1 = m + 1;
        if (lend == l) continue;
        if (fabsf(DGET(lend)) < fabsf(DGET(l))) { lend = lsv; l = lendsv; }
        if (lend > l) {
            for (;;) {
                int m2 = lend;
                if (l != lend) {
                    for (int mm = l; mm <= lend - 1; ++mm) {
                        float em = EGET(mm);
                        float tst = em * em;
                        if (tst <= (eps2 * fabsf(DGET(mm))) * fabsf(DGET(mm + 1)) + safmin) { m2 = mm; break; }
                    }
                }
                if (m2 < lend) ESET(m2, 0.f);
                float p = DGET(l);
                if (m2 == l) { DSET(l, p); ++l; if (l <= lend) continue; else break; }
                if (m2 == l + 1) {
                    float rt1, rt2, c, s;
                    slaev2_f(DGET(l), EGET(l), DGET(l + 1), rt1, rt2, c, s);
                    if (lane == 0) { rcl[cnt] = c; rsl[cnt] = s; rjl[cnt] = l; }
                    ++cnt;
                    DSET(l, rt1); DSET(l + 1, rt2); ESET(l, 0.f); l += 2;
                    if (l <= lend) continue; else break;
                }
                if (jtot == nmaxit) break;
                ++jtot;
                float g = (DGET(l + 1) - p) / (2.f * EGET(l));
                float r = slapy2_f(g, 1.f);
                g = DGET(m2) - p + EGET(l) / (g + (g >= 0.f ? fabsf(r) : -fabsf(r)));
                float s = 1.f, c = 1.f;
                p = 0.f;
                for (int i = m2 - 1; i >= l; --i) {
                    float ei = EGET(i);
                    float f = s * ei, bq = c * ei;
                    slartg_f(g, f, c, s, r);
                    if (i != m2 - 1) ESET(i + 1, r);
                    g = DGET(i + 1) - p;
                    r = (DGET(i) - g) * s + 2.f * c * bq;
                    p = s * r;
                    DSET(i + 1, g + p);
                    g = c * r - bq;
                    if (lane == 0) { rcl[cnt] = c; rsl[cnt] = -s; rjl[cnt] = i; }
                    ++cnt;
                }
                DSET(l, DGET(l) - p);
                ESET(l, g);
            }
        } else {
            for (;;) {
                int m2 = lend;
                if (l != lend) {
                    for (int mm = l; mm >= lend + 1; --mm) {
                        float em = EGET(mm - 1);
                        float tst = em * em;
                        if (tst <= (eps2 * fabsf(DGET(mm))) * fabsf(DGET(mm - 1)) + safmin) { m2 = mm; break; }
                    }
                }
                if (m2 > lend) ESET(m2 - 1, 0.f);
                float p = DGET(l);
                if (m2 == l) { DSET(l, p); --l; if (l >= lend) continue; else break; }
                if (m2 == l - 1) {
                    float rt1, rt2, c, s;
                    slaev2_f(DGET(l - 1), EGET(l - 1), DGET(l), rt1, rt2, c, s);
                    if (lane == 0) { rcl[cnt] = c; rsl[cnt] = s; rjl[cnt] = l - 1; }
                    ++cnt;
                    DSET(l - 1, rt1); DSET(l, rt2); ESET(l - 1, 0.f); l -= 2;
                    if (l >= lend) continue; else break;
                }
                if (jtot == nmaxit) break;
                ++jtot;
                float g = (DGET(l - 1) - p) / (2.f * EGET(l - 1));
                float r = slapy2_f(g, 1.f);
                g = DGET(m2) - p + EGET(l - 1) / (g + (g >= 0.f ? fabsf(r) : -fabsf(r)));
                float s = 1.f, c = 1.f;
                p = 0.f;
                for (int i = m2; i <= l - 1; ++i) {
                    float ei = EGET(i);
                    float f = s * ei, bq = c * ei;
                    slartg_f(g, f, c, s, r);
                    if (i != m2) ESET(i - 1, r);
                    g = DGET(i) - p;
                    r = (DGET(i + 1) - g) * s + 2.f * c * bq;
                    p = s * r;
                    DSET(i, g + p);
                    g = c * r - bq;
                    if (lane == 0) { rcl[cnt] = c; rsl[cnt] = s; rjl[cnt] = i; }
                    ++cnt;
                }
                DSET(l, DGET(l) - p);
                ESET(l - 1, g);
            }
        }
    }
    __syncthreads();
    int permreg = lane;
    for (int ii = 1; ii < 9; ++ii) {
        int i = ii - 1, kk = i;
        float p = DGET(i);
        for (int j = ii; j < 9; ++j) {
            float dj = DGET(j);
            if (dj < p) { kk = j; p = dj; }
        }
        if (kk != i) {
            float di = DGET(i);
            DSET(kk, di);
            DSET(i, p);
            int pi = __builtin_amdgcn_readlane(permreg, i);
            int pk = __builtin_amdgcn_readlane(permreg, kk);
            permreg = (lane == i) ? pk : permreg;
            permreg = (lane == kk) ? pi : permreg;
        }
    }
    int kcol = __builtin_amdgcn_readlane(permreg, 0);
    float v0reg = (lane == kcol) ? 1.f : 0.f;
    for (int t = cnt - 1; t >= 0; --t) {
        float c = rcl[t], s = rsl[t];
        int j = rjl[t];
        float a = lgetf(v0reg, j);
        float b2 = lgetf(v0reg, j + 1);
        float nj = c * a - s * b2;
        float nj1 = s * a + c * b2;
        v0reg = (lane == j) ? nj : v0reg;
        v0reg = (lane == j + 1) ? nj1 : v0reg;
    }
    for (int i = 7; i >= 0; --i) {
        float ti = lgetf(treg, i);
        if (ti == 0.f) continue;
        float avi = (lane >= i + 2 && lane <= 8) ? Am[lane * 9 + i] : 0.f;
        float contrib = 0.f;
        if (lane == i + 1) contrib = v0reg;
        else if (lane >= i + 2 && lane <= 8) contrib = avi * v0reg;
        float dot = wsum64(contrib) * ti;
        if (lane == i + 1) v0reg -= dot;
        else if (lane >= i + 2 && lane <= 8) v0reg -= avi * dot;
    }
    float sq = (lane < 9) ? v0reg * v0reg : 0.f;
    float nrm = sqrtf(wsum64(sq));
    if (lane < 9) out_e[bb * 9 + lane] = v0reg / nrm;
#undef AA
#undef DGET
#undef DSET
#undef EGET
#undef ESET
}

// ---------------------------------------------------------------------------
// launch
// ---------------------------------------------------------------------------
extern "C" void kernel_launch(void* const* d_in, const int* in_sizes, int n_in,
                              void* d_out, int out_size, void* d_ws, size_t ws_size,
                              hipStream_t stream) {
    const float* data = (const float*)d_in[0];
    const float* x_in = (const float*)d_in[1];
    const float* w1a = (const float*)d_in[2];
    const float* b1a = (const float*)d_in[3];
    const float* w1b = (const float*)d_in[4];
    const float* b1b = (const float*)d_in[5];
    const float* w2 = (const float*)d_in[6];
    const float* b2 = (const float*)d_in[7];
    const float* res_wa = (const float*)d_in[8];
    const float* res_ba = (const float*)d_in[9];
    const float* res_wb = (const float*)d_in[10];
    const float* res_bb = (const float*)d_in[11];
    const float* wl = (const float*)d_in[12];
    const float* bl = (const float*)d_in[13];
    float* out = (float*)d_out;

    // workspace layout
    double* gacc = (double*)d_ws;                       // 65 doubles (zeroed)
    float* xwx = (float*)((char*)d_ws + 1024);          // 16*45 floats
    float* fbase = (float*)((char*)d_ws + 16384);
    float* big0 = fbase;
    float* big1 = big0 + BB * CH * NN;
    float* big2 = big1 + BB * CH * NN;
    float* tbuf = big2 + BB * CH * NN;  // unused
    float* f5 = tbuf + BB * 4 * NN;
    float* invn = f5 + BB * 5 * NN;
    float* Sv = invn + BB * NN;
    int* idxb = (int*)(Sv + BB * CH);
    float* chAB = (float*)(idxb + BB * NN * 8);
    float* stA = chAB + 256;
    float* abA = stA + BB * CH * 2;
    float* stB = abA + BB * CH * 2;
    float* abB = stB + BB * CH * 2;
    float* g2ab = abB + BB * CH * 2;
    // kNN partials live in big2 (free until the res-blocks)
    float* knn_pd = big2;
    int* knn_pj = (int*)(big2 + BB * NN * JCH * 8);

    hipMemsetAsync(d_ws, 0, 1024, stream);

    k_conv1<<<16000, 256, 0, stream>>>(data, w1a, b1a, big0);
    k_chanstats<<<128, 256, 0, stream>>>(big0, chAB);
    k_gemm<<<dim3(2, 512), 256, 0, stream>>>(big0, w1b, b1b, big1, chAB, 1);  // h2 in big1
    k_invn<<<128, 256, 0, stream>>>(big1, invn);
    k_S<<<2048, 256, 0, stream>>>(big1, invn, Sv);
    k_Df<<<128, 256, 0, stream>>>(big1, invn, Sv, data, out, f5);
    k_knn_part<<<dim3(JCH, 8, BB), 256, 0, stream>>>(f5, knn_pd, knn_pj);
    k_knn_merge<<<125, 256, 0, stream>>>(knn_pd, knn_pj, idxb);
    k_gstats<<<250, 128, 0, stream>>>(f5, idxb, gacc);
    k_gfinal<<<1, 128, 0, stream>>>(gacc, w2, b2, g2ab);
    k_graphconv<<<2000, 256, 0, stream>>>(f5, idxb, w2, b2, g2ab, big0);  // x0 in big0

    float* xb = big0;
    float* hb = big1;
    for (int i = 0; i < 4; ++i) {
        k_gemm<<<dim3(2, 512), 256, 0, stream>>>(xb, res_wa + i * CH * CH, res_ba + i * CH, hb, nullptr, 0);
        k_rowstats<<<2048, 256, 0, stream>>>(hb, stA);
        k_finalize<<<1, 128, 0, stream>>>(stA, abA);
        k_gemm<<<dim3(2, 512), 256, 0, stream>>>(hb, res_wb + i * CH * CH, res_bb + i * CH, big2, abA, 2);
        k_rowstats<<<2048, 256, 0, stream>>>(big2, stB);
        k_finalize<<<1, 128, 0, stream>>>(stB, abB);
        k_resadd<<<4000, 256, 0, stream>>>(big2, abB, xb, hb);
        float* tmp = xb; xb = hb; hb = tmp;
    }

    k_logit<<<128, 256, 0, stream>>>(xb, wl, bl, out + BB * NN);
    k_xwx<<<16, 256, 0, stream>>>(out + BB * NN, x_in, xwx);
    k_eigh<<<16, 64, 0, stream>>>(xwx, out + 2 * BB * NN);
}

// Round 12
// 701.878 us; speedup vs baseline: 1.0318x; 1.0100x over previous
//
#include <hip/hip_runtime.h>
#include <math.h>

#define BB 16
#define NN 2000
#define CH 128
#define KNN 8
#define JCH 8
#define JSZ 250  // NN / JCH

// ---------------------------------------------------------------------------
// helpers
// ---------------------------------------------------------------------------
__device__ inline float wred(float v) {
    for (int off = 32; off > 0; off >>= 1) v += __shfl_down(v, off, 64);
    return v;
}

// conv1: c1[b,o,n] = sum_c w1a[o,c]*data[b,n,c] + b1a[o]
__global__ void k_conv1(const float* __restrict__ data, const float* __restrict__ w1a,
                        const float* __restrict__ b1a, float* __restrict__ c1) {
    int i = blockIdx.x * 256 + threadIdx.x;  // (b*128+o)*N+n
    if (i >= BB * CH * NN) return;
    int n = i % NN;
    int rest = i / NN;
    int o = rest & 127;
    int b = rest >> 7;
    const float4 d4 = *(const float4*)(data + (b * NN + n) * 4);
    const float4 w4 = *(const float4*)(w1a + o * 4);
    float acc = b1a[o];
    acc += w4.x * d4.x;
    acc += w4.y * d4.y;
    acc += w4.z * d4.z;
    acc += w4.w * d4.w;
    c1[i] = acc;
}

// per-channel bn stats over (b,n): 128 blocks
__global__ void k_chanstats(const float* __restrict__ src, float* __restrict__ chAB) {
    int o = blockIdx.x;
    int tid = threadIdx.x;
    float s = 0.f, ss = 0.f;
    for (int b = 0; b < BB; ++b) {
        const float* p = src + (b * CH + o) * NN;
        for (int n = tid; n < NN; n += 256) { float v = p[n]; s += v; ss += v * v; }
    }
    s = wred(s); ss = wred(ss);
    __shared__ float sh[8];
    int wid = tid >> 6, lane = tid & 63;
    if (lane == 0) { sh[wid] = s; sh[4 + wid] = ss; }
    __syncthreads();
    if (tid == 0) {
        float S0 = sh[0] + sh[1] + sh[2] + sh[3];
        float SS = sh[4] + sh[5] + sh[6] + sh[7];
        float m = S0 / (float)(BB * NN);
        float var = SS / (float)(BB * NN) - m * m;
        float a = rsqrtf(var + 1e-5f);
        chAB[o] = a;
        chAB[CH + o] = -m * a;
    }
}

// ---------------------------------------------------------------------------
// generic 128x128 GEMM over columns (b,n), with input transform.
// FMA accumulation order IDENTICAL to the r3 baseline — do not reorder.
// r17 staging (verified). r20/r21 128x128 rewrite SIGABRT'd twice; blocked.
// r24: mode 2 no longer reads a precomputed ab[] — the 8 single-block
// k_finalize dispatches were pure serial-latency bubbles (~3-6us each).
// Prologue recomputes (a,-m*a) per channel into LDS with the IDENTICAL
// expression sequence and b-loop order as k_finalize -> bit-identical
// values; 'ab' is the raw stats[] for mode 2.
// ---------------------------------------------------------------------------
__global__ __launch_bounds__(256) void k_gemm(const float* __restrict__ X, const float* __restrict__ W,
                                              const float* __restrict__ bias, float* __restrict__ Y,
                                              const float* __restrict__ ab, int mode) {
    int ot = blockIdx.x, by = blockIdx.y;
    int b = by >> 5, nt = by & 31;
    int n0 = nt * 64, o0 = ot * 64;
    int tid = threadIdx.x;
    int tx = tid & 15, ty = tid >> 4;
    __shared__ __align__(16) float Xs[32][64];
    __shared__ __align__(16) float Ws[32][68];
    __shared__ float sAB[CH][2];
    if (mode == 2) {  // r24: recompute finalize values (bit-identical order)
        int c = tid;
        if (c < CH) {
            float accv = 0.f;
            for (int bq = 0; bq < BB; ++bq) { float var = ab[(bq * CH + c) * 2 + 1]; accv += var / (var + 1e-5f); }
            float vc = accv / (float)BB;
            float sc = rsqrtf(vc + 1e-5f);
            float m = ab[(b * CH + c) * 2];
            float var = ab[(b * CH + c) * 2 + 1];
            float a = rsqrtf(var + 1e-5f) * sc;
            sAB[c][0] = a;
            sAB[c][1] = -m * a;
        }
        __syncthreads();
    }
    float acc[4][4] = {};
    for (int jc = 0; jc < 4; ++jc) {
        // X staging: 2048 floats = 512 quads; thread -> 2 quads
#pragma unroll
        for (int q = 0; q < 2; ++q) {
            int e4 = q * 256 + tid;          // 0..511
            int jj = e4 >> 4, nn4 = e4 & 15; // jj 0..31, nn4 0..15
            int j = jc * 32 + jj;
            int n = n0 + nn4 * 4;
            float4 v = make_float4(0.f, 0.f, 0.f, 0.f);
            if (n < NN) {  // quad all-in (n<=1996 => n+3<=1999) or all-out
                v = *(const float4*)&X[(b * CH + j) * NN + n];
                if (mode == 1) {
                    float a_ = ab[j], o_ = ab[CH + j];
                    v.x = fmaxf(a_ * v.x + o_, 0.f);
                    v.y = fmaxf(a_ * v.y + o_, 0.f);
                    v.z = fmaxf(a_ * v.z + o_, 0.f);
                    v.w = fmaxf(a_ * v.w + o_, 0.f);
                } else if (mode == 2) {
                    float a_ = sAB[j][0], o_ = sAB[j][1];
                    v.x = fmaxf(a_ * v.x + o_, 0.f);
                    v.y = fmaxf(a_ * v.y + o_, 0.f);
                    v.z = fmaxf(a_ * v.z + o_, 0.f);
                    v.w = fmaxf(a_ * v.w + o_, 0.f);
                }
            }
            *(float4*)&Xs[jj][nn4 * 4] = v;
        }
        // W staging: 2048 floats = 512 quads (contiguous in jj); transpose into Ws
#pragma unroll
        for (int q = 0; q < 2; ++q) {
            int e4 = q * 256 + tid;           // 0..511
            int oo = e4 >> 3, jj4 = e4 & 7;   // oo 0..63, jj4 0..7
            float4 wv4 = *(const float4*)&W[(o0 + oo) * CH + jc * 32 + jj4 * 4];
            Ws[jj4 * 4 + 0][oo] = wv4.x;
            Ws[jj4 * 4 + 1][oo] = wv4.y;
            Ws[jj4 * 4 + 2][oo] = wv4.z;
            Ws[jj4 * 4 + 3][oo] = wv4.w;
        }
        __syncthreads();
        for (int jj = 0; jj < 32; ++jj) {
            float4 wv = *(const float4*)&Ws[jj][ty * 4];
            float4 xv = *(const float4*)&Xs[jj][tx * 4];
            float wva[4] = {wv.x, wv.y, wv.z, wv.w};
            float xva[4] = {xv.x, xv.y, xv.z, xv.w};
#pragma unroll
            for (int a = 0; a < 4; ++a)
#pragma unroll
                for (int bq = 0; bq < 4; ++bq) acc[a][bq] += wva[a] * xva[bq];
        }
        __syncthreads();
    }
    for (int a = 0; a < 4; ++a) {
        int o = o0 + ty * 4 + a;
        float bi = bias[o];
        for (int q = 0; q < 4; ++q) {
            int n = n0 + tx * 4 + q;
            if (n < NN) Y[(b * CH + o) * NN + n] = acc[a][q] + bi;
        }
    }
}

// ---------------------------------------------------------------------------
// stage 1 tail: channel-norm, S, D, f5
// ---------------------------------------------------------------------------
__global__ void k_invn(const float* __restrict__ h2, float* __restrict__ invn) {
    int b = blockIdx.x >> 3, chunk = blockIdx.x & 7;
    int n = chunk * 256 + threadIdx.x;
    if (n >= NN) return;
    float acc = 0.f;
    for (int c = 0; c < CH; ++c) { float v = h2[(b * CH + c) * NN + n]; acc += v * v; }
    invn[b * NN + n] = 1.f / (sqrtf(acc) + 1e-5f);
}

__global__ void k_S(const float* __restrict__ h2, const float* __restrict__ invn, float* __restrict__ Sv) {
    int row = blockIdx.x;  // b*128+c
    int b = row >> 7;
    const float* p = h2 + row * NN;
    const float* iv = invn + b * NN;
    float s = 0.f;
    for (int n = threadIdx.x; n < NN; n += 256) s += p[n] * iv[n];
    s = wred(s);
    __shared__ float sh[4];
    int wid = threadIdx.x >> 6, lane = threadIdx.x & 63;
    if (lane == 0) sh[wid] = s;
    __syncthreads();
    if (threadIdx.x == 0) Sv[row] = sh[0] + sh[1] + sh[2] + sh[3];
}

__global__ void k_Df(const float* __restrict__ h2, const float* __restrict__ invn,
                     const float* __restrict__ Sv, const float* __restrict__ data,
                     float* __restrict__ outD, float* __restrict__ f5) {
    int b = blockIdx.x >> 3, chunk = blockIdx.x & 7;
    int n = chunk * 256 + threadIdx.x;
    if (n >= NN) return;
    float acc = 0.f;
    for (int c = 0; c < CH; ++c) acc += h2[(b * CH + c) * NN + n] * Sv[b * CH + c];
    float Ar = acc * invn[b * NN + n];
    float Dv = (Ar - 1.0f) / (float)NN;
    outD[b * NN + n] = Dv;
    const float4 d4 = *(const float4*)(data + (b * NN + n) * 4);
    f5[(b * 5 + 0) * NN + n] = d4.x;
    f5[(b * 5 + 1) * NN + n] = d4.y;
    f5[(b * 5 + 2) * NN + n] = d4.z;
    f5[(b * 5 + 3) * NN + n] = d4.w;
    f5[(b * 5 + 4) * NN + n] = fmaxf(tanhf(Dv), 0.f);
}

// ---------------------------------------------------------------------------
// kNN stage A (r16): branchless selection on separate (f32 d, i32 j) with
// single-native-compare CAS: 1 v_cmp_lt_f32 (vcc) + 4 v_cndmask, zero SALU.
// Tie-break-free strict < is selection-identical: no exact f32 ties among
// real candidates; self = +inf; pad sentinels never reach top-8.
// ---------------------------------------------------------------------------
__device__ __forceinline__ void cas_fj(float& da, int& ja, float& db, int& jb) {
    bool sw = db < da;
    float d0 = sw ? db : da;
    float d1 = sw ? da : db;
    int j0 = sw ? jb : ja;
    int j1 = sw ? ja : jb;
    da = d0; db = d1; ja = j0; jb = j1;
}

__global__ __launch_bounds__(256, 4) void k_knn_part(const float* __restrict__ f5,
                                                     float* __restrict__ pd, int* __restrict__ pj) {
    __shared__ float4 fs4[256];
    __shared__ float fs1[256];
    int jc = blockIdx.x, ic = blockIdx.y, b = blockIdx.z;
    int j0 = jc * JSZ;
    int tid = threadIdx.x;
    const float* fb = f5 + b * 5 * NN;
    if (tid < JSZ) {
        float4 v;
        v.x = fb[0 * NN + j0 + tid];
        v.y = fb[1 * NN + j0 + tid];
        v.z = fb[2 * NN + j0 + tid];
        v.w = fb[3 * NN + j0 + tid];
        fs4[tid] = v;
        fs1[tid] = fb[4 * NN + j0 + tid];
    } else {
        fs4[tid] = make_float4(1e18f, 1e18f, 1e18f, 1e18f);
        fs1[tid] = 1e18f;
    }
    __syncthreads();
    int i = ic * 256 + tid;
    if (i >= NN) return;
    float fi0 = fb[i], fi1 = fb[NN + i], fi2 = fb[2 * NN + i], fi3 = fb[3 * NN + i], fi4 = fb[4 * NN + i];
    const float DINF = __int_as_float(0x7f800000);
    float bd[8]; int bj[8];
#pragma unroll
    for (int q = 0; q < 8; ++q) { bd[q] = 1e30f; bj[q] = 0x7fffffff; }
    for (int g = 0; g < 256; g += 8) {
        float gd[8]; int gj[8];
#pragma unroll
        for (int k = 0; k < 8; ++k) {
            float4 fj = fs4[g + k];
            float f4 = fs1[g + k];
            float a0 = fi0 - fj.x, a1 = fi1 - fj.y, a2 = fi2 - fj.z, a3 = fi3 - fj.w, a4 = fi4 - f4;
            float dd = a0 * a0 + a1 * a1 + a2 * a2 + a3 * a3 + a4 * a4;
            int jj = j0 + g + k;
            gd[k] = (jj == i) ? DINF : dd;
            gj[k] = jj;
        }
        // Batcher odd-even mergesort for 8 (19 comparators), ascending
        cas_fj(gd[0], gj[0], gd[1], gj[1]); cas_fj(gd[2], gj[2], gd[3], gj[3]);
        cas_fj(gd[4], gj[4], gd[5], gj[5]); cas_fj(gd[6], gj[6], gd[7], gj[7]);
        cas_fj(gd[0], gj[0], gd[2], gj[2]); cas_fj(gd[1], gj[1], gd[3], gj[3]);
        cas_fj(gd[4], gj[4], gd[6], gj[6]); cas_fj(gd[5], gj[5], gd[7], gj[7]);
        cas_fj(gd[1], gj[1], gd[2], gj[2]); cas_fj(gd[5], gj[5], gd[6], gj[6]);
        cas_fj(gd[0], gj[0], gd[4], gj[4]); cas_fj(gd[1], gj[1], gd[5], gj[5]);
        cas_fj(gd[2], gj[2], gd[6], gj[6]); cas_fj(gd[3], gj[3], gd[7], gj[7]);
        cas_fj(gd[2], gj[2], gd[4], gj[4]); cas_fj(gd[3], gj[3], gd[5], gj[5]);
        cas_fj(gd[1], gj[1], gd[2], gj[2]); cas_fj(gd[3], gj[3], gd[4], gj[4]);
        cas_fj(gd[5], gj[5], gd[6], gj[6]);
        // lowest-8 of (bd asc ++ gd desc): elementwise min IN PLACE -> bitonic
#pragma unroll
        for (int q = 0; q < 8; ++q) {
            float yd = gd[7 - q]; int yj = gj[7 - q];
            bool kp = bd[q] < yd;
            bd[q] = kp ? bd[q] : yd;
            bj[q] = kp ? bj[q] : yj;
        }
        // bitonic cleanup of the 8-length bitonic sequence (12 CAS), in place
        cas_fj(bd[0], bj[0], bd[4], bj[4]); cas_fj(bd[1], bj[1], bd[5], bj[5]);
        cas_fj(bd[2], bj[2], bd[6], bj[6]); cas_fj(bd[3], bj[3], bd[7], bj[7]);
        cas_fj(bd[0], bj[0], bd[2], bj[2]); cas_fj(bd[1], bj[1], bd[3], bj[3]);
        cas_fj(bd[4], bj[4], bd[6], bj[6]); cas_fj(bd[5], bj[5], bd[7], bj[7]);
        cas_fj(bd[0], bj[0], bd[1], bj[1]); cas_fj(bd[2], bj[2], bd[3], bj[3]);
        cas_fj(bd[4], bj[4], bd[5], bj[5]); cas_fj(bd[6], bj[6], bd[7], bj[7]);
    }
    long base = ((long)(b * NN + i) * JCH + jc) * 8;
#pragma unroll
    for (int q = 0; q < 8; ++q) { pd[base + q] = bd[q]; pj[base + q] = bj[q]; }
}

// kNN stage B: 8-way merge of sorted partial lists (separate kernel — r12's
// fusion with gstats spilled registers and regressed; reverted).
__global__ __launch_bounds__(256) void k_knn_merge(const float* __restrict__ pd, const int* __restrict__ pj,
                                                   int* __restrict__ idxb) {
    int s = blockIdx.x * 256 + threadIdx.x;  // b*NN + i
    if (s >= BB * NN) return;
    const float* dl = pd + (long)s * JCH * 8;
    const int* jl = pj + (long)s * JCH * 8;
    int ptr[JCH];
#pragma unroll
    for (int c = 0; c < JCH; ++c) ptr[c] = 0;
    for (int q = 0; q < 8; ++q) {
        float best = 1e38f; int bestj = 0x7fffffff; int bc = 0;
#pragma unroll
        for (int c = 0; c < JCH; ++c) {
            if (ptr[c] < 8) {
                float d = dl[c * 8 + ptr[c]];
                int j = jl[c * 8 + ptr[c]];
                if (d < best || (d == best && j < bestj)) { best = d; bestj = j; bc = c; }
            }
        }
        idxb[s * 8 + q] = bestj;
        ++ptr[bc];
    }
}

// ---------------------------------------------------------------------------
// graph-feature statistics: 10 means + 55 second moments (f64 accumulators)
// ---------------------------------------------------------------------------
__global__ __launch_bounds__(128) void k_gstats(const float* __restrict__ f5, const int* __restrict__ idxb,
                                                double* __restrict__ gacc) {
    int s = blockIdx.x * 128 + threadIdx.x;
    float acc[65];
#pragma unroll
    for (int q = 0; q < 65; ++q) acc[q] = 0.f;
    if (s < BB * NN) {
        int b = s / NN, n = s - b * NN;
        float fo[5];
#pragma unroll
        for (int c = 0; c < 5; ++c) fo[c] = f5[(b * 5 + c) * NN + n];
        float sd[5] = {0, 0, 0, 0, 0};
        float sdd[15];
#pragma unroll
        for (int q = 0; q < 15; ++q) sdd[q] = 0.f;
        for (int k = 0; k < 8; ++k) {
            int j = idxb[s * 8 + k];
            float df[5];
#pragma unroll
            for (int c = 0; c < 5; ++c) df[c] = fo[c] - f5[(b * 5 + c) * NN + j];
#pragma unroll
            for (int c = 0; c < 5; ++c) sd[c] += df[c];
            int t = 0;
#pragma unroll
            for (int c = 0; c < 5; ++c)
#pragma unroll
                for (int d2 = c; d2 < 5; ++d2) { sdd[t] += df[c] * df[d2]; ++t; }
        }
#pragma unroll
        for (int c = 0; c < 5; ++c) { acc[c] = 8.f * fo[c]; acc[5 + c] = sd[c]; }
        int t = 10, sc = 0;
        for (int p = 0; p < 10; ++p)
            for (int q = p; q < 10; ++q) {
                float v;
                if (q < 5) v = 8.f * fo[p] * fo[q];
                else if (p < 5) v = fo[p] * sd[q - 5];
                else { v = sdd[sc]; ++sc; }
                acc[t++] = v;
            }
    }
#pragma unroll 1
    for (int q = 0; q < 65; ++q) {
        float v = acc[q];
        for (int off = 32; off > 0; off >>= 1) v += __shfl_down(v, off, 64);
        acc[q] = v;
    }
    __shared__ float sh[2][65];
    int lane = threadIdx.x & 63, wid = threadIdx.x >> 6;
    if (lane == 0) {
        for (int q = 0; q < 65; ++q) sh[wid][q] = acc[q];
    }
    __syncthreads();
    if (threadIdx.x < 65) {
        float tot = sh[0][threadIdx.x] + sh[1][threadIdx.x];
        atomicAdd(&gacc[threadIdx.x], (double)tot);
    }
}

__global__ void k_gfinal(const double* __restrict__ gacc, const float* __restrict__ w2,
                         const float* __restrict__ b2, float* __restrict__ g2ab) {
    int o = threadIdx.x;
    if (o >= 128) return;
    double inv = 1.0 / (double)(BB * NN * 8);
    double Wr[10];
    for (int c = 0; c < 10; ++c) Wr[c] = (double)w2[o * 10 + c];
    double gm[10];
    for (int c = 0; c < 10; ++c) gm[c] = gacc[c] * inv;
    double b0 = (double)b2[o];
    double mean = b0;
    for (int c = 0; c < 10; ++c) mean += Wr[c] * gm[c];
    double e2 = b0 * b0 + 2.0 * b0 * (mean - b0);
    int t = 10;
    for (int p = 0; p < 10; ++p)
        for (int q = p; q < 10; ++q) {
            double G = gacc[t] * inv; ++t;
            double contrib = Wr[p] * Wr[q] * G;
            e2 += (p == q) ? contrib : 2.0 * contrib;
        }
    double var = e2 - mean * mean;
    double a = 1.0 / sqrt(var + 1e-5);
    g2ab[o] = (float)a;
    g2ab[128 + o] = (float)(-mean * a);
}

// graph conv + max over k + bn + relu (bn commutes with max since scale>0)
__global__ __launch_bounds__(256) void k_graphconv(const float* __restrict__ f5, const int* __restrict__ idxb,
                                                   const float* __restrict__ w2, const float* __restrict__ b2,
                                                   const float* __restrict__ g2ab, float* __restrict__ x0) {
    __shared__ float ws[1280], bs[128];
    __shared__ float fo_s[16][5], fnb_s[16][8][5];
    __shared__ int idxs[16][8];
    int b = blockIdx.x / 125, tile = blockIdx.x % 125;
    int nbase = tile * 16;
    int tid = threadIdx.x;
    for (int e = tid; e < 1280; e += 256) ws[e] = w2[e];
    if (tid < 128) bs[tid] = b2[tid];
    if (tid < 128) { int nn = tid >> 3, k = tid & 7; idxs[nn][k] = idxb[(b * NN + nbase + nn) * 8 + k]; }
    if (tid >= 128 && tid < 208) { int e = tid - 128; int nn = e / 5, c = e % 5; fo_s[nn][c] = f5[(b * 5 + c) * NN + nbase + nn]; }
    __syncthreads();
    for (int e = tid; e < 640; e += 256) {
        int nn = e / 40, r = e % 40, k = r / 5, c = r % 5;
        fnb_s[nn][k][c] = f5[(b * 5 + c) * NN + idxs[nn][k]];
    }
    __syncthreads();
    int nn = tid & 15, og = tid >> 4;
    float fo[5];
#pragma unroll
    for (int c = 0; c < 5; ++c) fo[c] = fo_s[nn][c];
    for (int oo = 0; oo < 8; ++oo) {
        int o = og * 8 + oo;
        float base = bs[o];
        float wn[5];
#pragma unroll
        for (int c = 0; c < 5; ++c) {
            float w1 = ws[o * 10 + c], w5 = ws[o * 10 + 5 + c];
            base += (w1 + w5) * fo[c];
            wn[c] = w5;
        }
        float mx = -1e30f;
        for (int k = 0; k < 8; ++k) {
            float v = base;
#pragma unroll
            for (int c = 0; c < 5; ++c) v -= wn[c] * fnb_s[nn][k][c];
            mx = fmaxf(mx, v);
        }
        float y = fmaxf(g2ab[o] * mx + g2ab[128 + o], 0.f);
        x0[(b * CH + o) * NN + nbase + nn] = y;
    }
}

// ---------------------------------------------------------------------------
// res-block support — r11 structure. k_finalize ELIMINATED in r24 (its 8
// single-block dispatches were serial bubbles); consumers recompute from
// stats with identical expression order (k_gemm mode-2 prologue; k_resadd
// 2-channel prologue).
// ---------------------------------------------------------------------------
__global__ void k_rowstats(const float* __restrict__ src, float* __restrict__ stats) {
    int row = blockIdx.x;  // b*128+c
    const float* p = src + row * NN;
    float s = 0.f, ss = 0.f;
    for (int n = threadIdx.x; n < NN; n += 256) { float v = p[n]; s += v; ss += v * v; }
    s = wred(s); ss = wred(ss);
    __shared__ float sh[8];
    int wid = threadIdx.x >> 6, lane = threadIdx.x & 63;
    if (lane == 0) { sh[wid] = s; sh[4 + wid] = ss; }
    __syncthreads();
    if (threadIdx.x == 0) {
        float S0 = sh[0] + sh[1] + sh[2] + sh[3];
        float SS = sh[4] + sh[5] + sh[6] + sh[7];
        float m = S0 / (float)NN;
        float var = SS / (float)NN - m * m;
        stats[row * 2] = m;
        stats[row * 2 + 1] = var;
    }
}

// r22: float4 vectorized. r24: computes its own (a,o) pairs from stats —
// a block spans <=2 rows (1024 elems < NN, 4|NN); threads 0/1 compute them
// into LDS with k_finalize's exact expression order -> bit-identical.
__global__ void k_resadd(const float* __restrict__ Bm, const float* __restrict__ stats,
                         const float* __restrict__ x, float* __restrict__ y) {
    __shared__ float sA[2][2];
    int blkbase = blockIdx.x * 256 * 4;
    int bc0 = blkbase / NN;
    if (threadIdx.x < 2) {
        int bc = bc0 + threadIdx.x;
        if (bc < BB * CH) {
            int c = bc & (CH - 1);
            float accv = 0.f;
            for (int bq = 0; bq < BB; ++bq) { float var = stats[(bq * CH + c) * 2 + 1]; accv += var / (var + 1e-5f); }
            float vc = accv / (float)BB;
            float sc = rsqrtf(vc + 1e-5f);
            float m = stats[bc * 2];
            float var = stats[bc * 2 + 1];
            float a = rsqrtf(var + 1e-5f) * sc;
            sA[threadIdx.x][0] = a;
            sA[threadIdx.x][1] = -m * a;
        }
    }
    __syncthreads();
    int i4 = blockIdx.x * 256 + threadIdx.x;  // quad index
    if (i4 >= BB * CH * NN / 4) return;
    int base = i4 * 4;
    int bc = base / NN;
    int sel = bc - bc0;  // 0 or 1
    float a_ = sA[sel][0], o_ = sA[sel][1];
    const float4 Bv = *(const float4*)(Bm + base);
    const float4 xv = *(const float4*)(x + base);
    float4 yv;
    yv.x = fmaxf(a_ * Bv.x + o_ + xv.x, 0.f);
    yv.y = fmaxf(a_ * Bv.y + o_ + xv.y, 0.f);
    yv.z = fmaxf(a_ * Bv.z + o_ + xv.z, 0.f);
    yv.w = fmaxf(a_ * Bv.w + o_ + xv.w, 0.f);
    *(float4*)(y + base) = yv;
}

// ---------------------------------------------------------------------------
// logit (separate — r10 lesson: never move work into a smaller grid)
// ---------------------------------------------------------------------------
__global__ void k_logit(const float* __restrict__ x4, const float* __restrict__ wl,
                        const float* __restrict__ bl, float* __restrict__ outLogit) {
    int b = blockIdx.x >> 3, chunk = blockIdx.x & 7;
    int n = chunk * 256 + threadIdx.x;
    if (n >= NN) return;
    float acc = 0.f;
    for (int c = 0; c < CH; ++c) acc += wl[c] * x4[(b * CH + c) * NN + n];
    outLogit[b * NN + n] = acc + bl[0];
}

__global__ __launch_bounds__(256) void k_xwx(const float* __restrict__ logit, const float* __restrict__ x_in,
                                             float* __restrict__ XwX) {
    int b = blockIdx.x;
    int tid = threadIdx.x;
    float a[45];
#pragma unroll
    for (int q = 0; q < 45; ++q) a[q] = 0.f;
    for (int n = tid; n < NN; n += 256) {
        float lg = logit[b * NN + n];
        float w = fmaxf(tanhf(lg), 0.f);
        const float* xp = x_in + (b * NN + n) * 4;
        float px = xp[0], py = xp[1], z = xp[2], wq = xp[3];
        float X9[9] = {z * px, z * py, z, wq * px, wq * py, wq, px, py, 1.f};
        int t = 0;
#pragma unroll
        for (int p = 0; p < 9; ++p) {
            float wp = w * X9[p];
#pragma unroll
            for (int q = p; q < 9; ++q) { a[t] += wp * X9[q]; ++t; }
        }
    }
#pragma unroll 1
    for (int q = 0; q < 45; ++q) {
        float v = a[q];
        for (int off = 32; off > 0; off >>= 1) v += __shfl_down(v, off, 64);
        a[q] = v;
    }
    __shared__ float sh[4][45];
    int lane = tid & 63, wid = tid >> 6;
    if (lane == 0) {
        for (int q = 0; q < 45; ++q) sh[wid][q] = a[q];
    }
    __syncthreads();
    if (tid < 45) XwX[b * 45 + tid] = sh[0][tid] + sh[1][tid] + sh[2][tid] + sh[3][tid];
}

// ---------------------------------------------------------------------------
// 9x9 symmetric eigensolver — faithful LAPACK ssyevd (f32) emulation:
// ssytd2 (lower) + ssteqr + sormtr. ARITHMETIC verified — unchanged.
// r19: batched LDS reads; lane-0 publishes guarded by __syncthreads() pairs.
// r23: Householder outer i-loop de-unrolled (runtime i, uniform-guarded
// unrolled inner loops) — icache-stream fix, verified passing.
// ---------------------------------------------------------------------------
__device__ __forceinline__ float lgetf(float reg, int i) {
    return __int_as_float(__builtin_amdgcn_readlane(__float_as_int(reg), i));
}
__device__ __forceinline__ float wsum64(float v) {
    for (int off = 32; off > 0; off >>= 1) v += __shfl_xor(v, off, 64);
    return v;
}

__device__ inline float slapy2_f(float x, float y) {
    float xa = fabsf(x), ya = fabsf(y);
    float w = fmaxf(xa, ya), z = fminf(xa, ya);
    if (z == 0.f) return w;
    float q = z / w;
    return w * sqrtf(1.f + q * q);
}

__device__ inline void slartg_f(float f, float g, float& c, float& s, float& r) {
    if (g == 0.f) { c = 1.f; s = 0.f; r = f; }
    else if (f == 0.f) { c = 0.f; s = (g > 0.f ? 1.f : -1.f); r = fabsf(g); }
    else {
        float d = sqrtf(f * f + g * g);
        c = fabsf(f) / d;
        r = (f >= 0.f) ? d : -d;
        s = g / r;
    }
}

__device__ void slaev2_f(float a, float b, float c, float& rt1, float& rt2, float& cs1, float& sn1) {
    float sm = a + c, df = a - c;
    float adf = fabsf(df), tb = b + b, ab = fabsf(tb);
    float acmx, acmn;
    if (fabsf(a) > fabsf(c)) { acmx = a; acmn = c; } else { acmx = c; acmn = a; }
    float rt;
    if (adf > ab) { float q = ab / adf; rt = adf * sqrtf(1.f + q * q); }
    else if (adf < ab) { float q = adf / ab; rt = ab * sqrtf(1.f + q * q); }
    else rt = ab * sqrtf(2.f);
    int sgn1;
    if (sm < 0.f) { rt1 = 0.5f * (sm - rt); sgn1 = -1; rt2 = (acmx / rt1) * acmn - (b / rt1) * b; }
    else if (sm > 0.f) { rt1 = 0.5f * (sm + rt); sgn1 = 1; rt2 = (acmx / rt1) * acmn - (b / rt1) * b; }
    else { rt1 = 0.5f * rt; rt2 = -0.5f * rt; sgn1 = 1; }
    float cs; int sgn2;
    if (df >= 0.f) { cs = df + rt; sgn2 = 1; } else { cs = df - rt; sgn2 = -1; }
    float acs = fabsf(cs);
    if (acs > ab) {
        float ct = -tb / cs;
        sn1 = 1.f / sqrtf(1.f + ct * ct);
        cs1 = ct * sn1;
    } else {
        if (ab == 0.f) { cs1 = 1.f; sn1 = 0.f; }
        else { float tn = -cs / tb; cs1 = 1.f / sqrtf(1.f + tn * tn); sn1 = tn * cs1; }
    }
    if (sgn1 == sgn2) { float tn = cs1; cs1 = -sn1; sn1 = tn; }
}

#define ROTLOG_MAX 2560

__global__ __launch_bounds__(64) void k_eigh(const float* __restrict__ XwX, float* __restrict__ out_e) {
    __shared__ float Am[81];
    __shared__ float rcl[ROTLOG_MAX], rsl[ROTLOG_MAX];
    __shared__ int rjl[ROTLOG_MAX];
    int bb = blockIdx.x;
    int lane = threadIdx.x;
#define AA(i, j) Am[(i) * 9 + (j)]
#define DGET(i) lgetf(dreg, (i))
#define DSET(i, v) do { float _v = (v); dreg = (lane == (i)) ? _v : dreg; } while (0)
#define EGET(i) lgetf(ereg, (i))
#define ESET(i, v) do { float _v = (v); ereg = (lane == (i)) ? _v : ereg; } while (0)
    {
        const float* src = XwX + bb * 45;
        for (int e2 = lane; e2 < 81; e2 += 64) {
            int r0 = e2 / 9, c0 = e2 % 9;
            int a0 = r0 < c0 ? r0 : c0, b0 = r0 < c0 ? c0 : r0;
            int t = a0 * 9 - (a0 * (a0 - 1)) / 2 + (b0 - a0);
            Am[e2] = src[t];
        }
    }
    __syncthreads();
    float dreg = 0.f, ereg = 0.f, treg = 0.f;
    int cnt = 0;
    // r23: runtime i, uniform-guarded unrolled inner loops (see header).
    for (int i = 0; i < 8; ++i) {
        float alpha = AA(i + 1, i);
        float xn2 = 0.f;
#pragma unroll
        for (int j = 0; j < 9; ++j)
            if (j >= i + 2) xn2 += AA(j, i) * AA(j, i);
        float taui;
        if (xn2 == 0.f) { taui = 0.f; ESET(i, alpha); }
        else {
            float xnorm = sqrtf(xn2);
            float beta = slapy2_f(alpha, xnorm);
            beta = (alpha >= 0.f) ? -beta : beta;
            taui = (beta - alpha) / beta;
            float scl = 1.f / (alpha - beta);
            float colv[9];
#pragma unroll
            for (int j = 0; j < 9; ++j)
                if (j >= i + 2) colv[j] = AA(j, i) * scl;
            __syncthreads();
            if (lane == 0) {
#pragma unroll
                for (int j = 0; j < 9; ++j)
                    if (j >= i + 2) AA(j, i) = colv[j];
            }
            __syncthreads();
            ESET(i, beta);
            float p[9], w[9];
#pragma unroll
            for (int j = 0; j < 9; ++j)
                if (j >= i + 1) {
                    float acc = AA(j, i + 1);
#pragma unroll
                    for (int k2 = 0; k2 < 9; ++k2)
                        if (k2 >= i + 2) acc += AA(j, k2) * AA(k2, i);
                    p[j] = taui * acc;
                }
            float dot = 0.f;
#pragma unroll
            for (int j = 0; j < 9; ++j) {
                if (j == i + 1) dot = p[j];                 // assign (order: first)
                else if (j >= i + 2) dot += p[j] * AA(j, i);
            }
            float alpha2 = -0.5f * taui * dot;
#pragma unroll
            for (int j = 0; j < 9; ++j) {
                if (j == i + 1) w[j] = p[j] + alpha2;
                else if (j >= i + 2) w[j] = p[j] + alpha2 * AA(j, i);
            }
            float updv[9][9];
#pragma unroll
            for (int j = 0; j < 9; ++j)
                if (j >= i + 1) {
                    float vj = (j == i + 1) ? 1.f : AA(j, i);
#pragma unroll
                    for (int k2 = 0; k2 < 9; ++k2)
                        if (k2 >= i + 1) {
                            float vk = (k2 == i + 1) ? 1.f : AA(k2, i);
                            updv[j][k2] = AA(j, k2) - (vj * w[k2] + w[j] * vk);
                        }
                }
            __syncthreads();
            if (lane == 0) {
#pragma unroll
                for (int j = 0; j < 9; ++j)
                    if (j >= i + 1) {
#pragma unroll
                        for (int k2 = 0; k2 < 9; ++k2)
                            if (k2 >= i + 1) AA(j, k2) = updv[j][k2];
                    }
            }
            __syncthreads();
        }
        treg = (lane == i) ? taui : treg;
    }
    __syncthreads();
    dreg = (lane < 9) ? Am[lane * 10] : 0.f;
    const float eps = 5.9604645e-08f;
    const float eps2 = 3.5527137e-15f;
    const float safmin = 1.17549435e-38f;
    const int n = 9;
    int nmaxit = n * 30, jtot = 0;
    int l1 = 0;
    while (l1 <= n - 1) {
        if (l1 > 0) ESET(l1 - 1, 0.f);
        int m = n - 1;
        for (int mm = l1; mm <= n - 2; ++mm) {
            float tst = fabsf(EGET(mm));
            if (tst == 0.f) { m = mm; break; }
            if (tst <= (sqrtf(fabsf(DGET(mm))) * sqrtf(fabsf(DGET(mm + 1)))) * eps) { ESET(mm, 0.f); m = mm; break; }
        }
        int l = l1, lsv = l, lend = m, lendsv = lend;
        l1 = m + 1;
        if (lend == l) continue;
        if (fabsf(DGET(lend)) < fabsf(DGET(l))) { lend = lsv; l = lendsv; }
        if (lend > l) {
            for (;;) {
                int m2 = lend;
                if (l != lend) {
                    for (int mm = l; mm <= lend - 1; ++mm) {
                        float em = EGET(mm);
                        float tst = em * em;
                        if (tst <= (eps2 * fabsf(DGET(mm))) * fabsf(DGET(mm + 1)) + safmin) { m2 = mm; break; }
                    }
                }
                if (m2 < lend) ESET(m2, 0.f);
                float p = DGET(l);
                if (m2 == l) { DSET(l, p); ++l; if (l <= lend) continue; else break; }
                if (m2 == l + 1) {
                    float rt1, rt2, c, s;
                    slaev2_f(DGET(l), EGET(l), DGET(l + 1), rt1, rt2, c, s);
                    if (lane == 0) { rcl[cnt] = c; rsl[cnt] = s; rjl[cnt] = l; }
                    ++cnt;
                    DSET(l, rt1); DSET(l + 1, rt2); ESET(l, 0.f); l += 2;
                    if (l <= lend) continue; else break;
                }
                if (jtot == nmaxit) break;
                ++jtot;
                float g = (DGET(l + 1) - p) / (2.f * EGET(l));
                float r = slapy2_f(g, 1.f);
                g = DGET(m2) - p + EGET(l) / (g + (g >= 0.f ? fabsf(r) : -fabsf(r)));
                float s = 1.f, c = 1.f;
                p = 0.f;
                for (int i = m2 - 1; i >= l; --i) {
                    float ei = EGET(i);
                    float f = s * ei, bq = c * ei;
                    slartg_f(g, f, c, s, r);
                    if (i != m2 - 1) ESET(i + 1, r);
                    g = DGET(i + 1) - p;
                    r = (DGET(i) - g) * s + 2.f * c * bq;
                    p = s * r;
                    DSET(i + 1, g + p);
                    g = c * r - bq;
                    if (lane == 0) { rcl[cnt] = c; rsl[cnt] = -s; rjl[cnt] = i; }
                    ++cnt;
                }
                DSET(l, DGET(l) - p);
                ESET(l, g);
            }
        } else {
            for (;;) {
                int m2 = lend;
                if (l != lend) {
                    for (int mm = l; mm >= lend + 1; --mm) {
                        float em = EGET(mm - 1);
                        float tst = em * em;
                        if (tst <= (eps2 * fabsf(DGET(mm))) * fabsf(DGET(mm - 1)) + safmin) { m2 = mm; break; }
                    }
                }
                if (m2 > lend) ESET(m2 - 1, 0.f);
                float p = DGET(l);
                if (m2 == l) { DSET(l, p); --l; if (l >= lend) continue; else break; }
                if (m2 == l - 1) {
                    float rt1, rt2, c, s;
                    slaev2_f(DGET(l - 1), EGET(l - 1), DGET(l), rt1, rt2, c, s);
                    if (lane == 0) { rcl[cnt] = c; rsl[cnt] = s; rjl[cnt] = l - 1; }
                    ++cnt;
                    DSET(l - 1, rt1); DSET(l, rt2); ESET(l - 1, 0.f); l -= 2;
                    if (l >= lend) continue; else break;
                }
                if (jtot == nmaxit) break;
                ++jtot;
                float g = (DGET(l - 1) - p) / (2.f * EGET(l - 1));
                float r = slapy2_f(g, 1.f);
                g = DGET(m2) - p + EGET(l - 1) / (g + (g >= 0.f ? fabsf(r) : -fabsf(r)));
                float s = 1.f, c = 1.f;
                p = 0.f;
                for (int i = m2; i <= l - 1; ++i) {
                    float ei = EGET(i);
                    float f = s * ei, bq = c * ei;
                    slartg_f(g, f, c, s, r);
                    if (i != m2) ESET(i - 1, r);
                    g = DGET(i) - p;
                    r = (DGET(i + 1) - g) * s + 2.f * c * bq;
                    p = s * r;
                    DSET(i, g + p);
                    g = c * r - bq;
                    if (lane == 0) { rcl[cnt] = c; rsl[cnt] = s; rjl[cnt] = i; }
                    ++cnt;
                }
                DSET(l, DGET(l) - p);
                ESET(l - 1, g);
            }
        }
    }
    __syncthreads();
    int permreg = lane;
    for (int ii = 1; ii < 9; ++ii) {
        int i = ii - 1, kk = i;
        float p = DGET(i);
        for (int j = ii; j < 9; ++j) {
            float dj = DGET(j);
            if (dj < p) { kk = j; p = dj; }
        }
        if (kk != i) {
            float di = DGET(i);
            DSET(kk, di);
            DSET(i, p);
            int pi = __builtin_amdgcn_readlane(permreg, i);
            int pk = __builtin_amdgcn_readlane(permreg, kk);
            permreg = (lane == i) ? pk : permreg;
            permreg = (lane == kk) ? pi : permreg;
        }
    }
    int kcol = __builtin_amdgcn_readlane(permreg, 0);
    float v0reg = (lane == kcol) ? 1.f : 0.f;
    for (int t = cnt - 1; t >= 0; --t) {
        float c = rcl[t], s = rsl[t];
        int j = rjl[t];
        float a = lgetf(v0reg, j);
        float b2 = lgetf(v0reg, j + 1);
        float nj = c * a - s * b2;
        float nj1 = s * a + c * b2;
        v0reg = (lane == j) ? nj : v0reg;
        v0reg = (lane == j + 1) ? nj1 : v0reg;
    }
    for (int i = 7; i >= 0; --i) {
        float ti = lgetf(treg, i);
        if (ti == 0.f) continue;
        float avi = (lane >= i + 2 && lane <= 8) ? Am[lane * 9 + i] : 0.f;
        float contrib = 0.f;
        if (lane == i + 1) contrib = v0reg;
        else if (lane >= i + 2 && lane <= 8) contrib = avi * v0reg;
        float dot = wsum64(contrib) * ti;
        if (lane == i + 1) v0reg -= dot;
        else if (lane >= i + 2 && lane <= 8) v0reg -= avi * dot;
    }
    float sq = (lane < 9) ? v0reg * v0reg : 0.f;
    float nrm = sqrtf(wsum64(sq));
    if (lane < 9) out_e[bb * 9 + lane] = v0reg / nrm;
#undef AA
#undef DGET
#undef DSET
#undef EGET
#undef ESET
}

// ---------------------------------------------------------------------------
// launch
// ---------------------------------------------------------------------------
extern "C" void kernel_launch(void* const* d_in, const int* in_sizes, int n_in,
                              void* d_out, int out_size, void* d_ws, size_t ws_size,
                              hipStream_t stream) {
    const float* data = (const float*)d_in[0];
    const float* x_in = (const float*)d_in[1];
    const float* w1a = (const float*)d_in[2];
    const float* b1a = (const float*)d_in[3];
    const float* w1b = (const float*)d_in[4];
    const float* b1b = (const float*)d_in[5];
    const float* w2 = (const float*)d_in[6];
    const float* b2 = (const float*)d_in[7];
    const float* res_wa = (const float*)d_in[8];
    const float* res_ba = (const float*)d_in[9];
    const float* res_wb = (const float*)d_in[10];
    const float* res_bb = (const float*)d_in[11];
    const float* wl = (const float*)d_in[12];
    const float* bl = (const float*)d_in[13];
    float* out = (float*)d_out;

    // workspace layout
    double* gacc = (double*)d_ws;                       // 65 doubles (zeroed)
    float* xwx = (float*)((char*)d_ws + 1024);          // 16*45 floats
    float* fbase = (float*)((char*)d_ws + 16384);
    float* big0 = fbase;
    float* big1 = big0 + BB * CH * NN;
    float* big2 = big1 + BB * CH * NN;
    float* tbuf = big2 + BB * CH * NN;  // unused
    float* f5 = tbuf + BB * 4 * NN;
    float* invn = f5 + BB * 5 * NN;
    float* Sv = invn + BB * NN;
    int* idxb = (int*)(Sv + BB * CH);
    float* chAB = (float*)(idxb + BB * NN * 8);
    float* stA = chAB + 256;
    float* abA = stA + BB * CH * 2;   // unused since r24
    float* stB = abA + BB * CH * 2;
    float* abB = stB + BB * CH * 2;   // unused since r24
    float* g2ab = abB + BB * CH * 2;
    // kNN partials live in big2 (free until the res-blocks)
    float* knn_pd = big2;
    int* knn_pj = (int*)(big2 + BB * NN * JCH * 8);

    hipMemsetAsync(d_ws, 0, 1024, stream);

    k_conv1<<<16000, 256, 0, stream>>>(data, w1a, b1a, big0);
    k_chanstats<<<128, 256, 0, stream>>>(big0, chAB);
    k_gemm<<<dim3(2, 512), 256, 0, stream>>>(big0, w1b, b1b, big1, chAB, 1);  // h2 in big1
    k_invn<<<128, 256, 0, stream>>>(big1, invn);
    k_S<<<2048, 256, 0, stream>>>(big1, invn, Sv);
    k_Df<<<128, 256, 0, stream>>>(big1, invn, Sv, data, out, f5);
    k_knn_part<<<dim3(JCH, 8, BB), 256, 0, stream>>>(f5, knn_pd, knn_pj);
    k_knn_merge<<<125, 256, 0, stream>>>(knn_pd, knn_pj, idxb);
    k_gstats<<<250, 128, 0, stream>>>(f5, idxb, gacc);
    k_gfinal<<<1, 128, 0, stream>>>(gacc, w2, b2, g2ab);
    k_graphconv<<<2000, 256, 0, stream>>>(f5, idxb, w2, b2, g2ab, big0);  // x0 in big0

    float* xb = big0;
    float* hb = big1;
    for (int i = 0; i < 4; ++i) {
        k_gemm<<<dim3(2, 512), 256, 0, stream>>>(xb, res_wa + i * CH * CH, res_ba + i * CH, hb, nullptr, 0);
        k_rowstats<<<2048, 256, 0, stream>>>(hb, stA);
        k_gemm<<<dim3(2, 512), 256, 0, stream>>>(hb, res_wb + i * CH * CH, res_bb + i * CH, big2, stA, 2);
        k_rowstats<<<2048, 256, 0, stream>>>(big2, stB);
        k_resadd<<<4000, 256, 0, stream>>>(big2, stB, xb, hb);
        float* tmp = xb; xb = hb; hb = tmp;
    }

    k_logit<<<128, 256, 0, stream>>>(xb, wl, bl, out + BB * NN);
    k_xwx<<<16, 256, 0, stream>>>(out + BB * NN, x_in, xwx);
    k_eigh<<<16, 64, 0, stream>>>(xwx, out + 2 * BB * NN);
}